// Round 5
// baseline (406.191 us; speedup 1.0000x reference)
//
#include <hip/hip_runtime.h>
#include <math.h>
#include <stdint.h>

#define B_ 4
#define C_ 256
#define HW_ 4096
#define G_ 8
#define H_ 4
#define DH_ 64
#define GRP_ELEMS (32 * HW_)             // 131072
#define NCHUNK 16
#define CHUNK_ELEMS (GRP_ELEMS / NCHUNK) // 8192
#define EPS 1e-5f
#define NT_ (HW_ / 64)                   // 64 j-tiles
#define QSCALE 0.04508422f               // (1/32) * log2(e)

typedef __attribute__((ext_vector_type(8))) short short8;
typedef __attribute__((ext_vector_type(4))) float f32x4;
typedef const __attribute__((address_space(1))) uint32_t* gas1_t;
typedef __attribute__((address_space(3))) uint32_t* las3_t;

__device__ __forceinline__ ushort f2bf(float x) {
    unsigned u = __builtin_bit_cast(unsigned, x);
    u += 0x7FFFu + ((u >> 16) & 1u);
    return (ushort)(u >> 16);
}

// ---------------- GroupNorm stage 1: deterministic partial sums -----------
__global__ __launch_bounds__(256) void gn_partial(const float* __restrict__ x,
                                                  float* __restrict__ part) {
    int bg = blockIdx.x >> 4;
    int chunk = blockIdx.x & 15;
    const float4* p = (const float4*)(x + (size_t)bg * GRP_ELEMS + (size_t)chunk * CHUNK_ELEMS);
    int t = threadIdx.x;
    float s = 0.f, ss = 0.f;
#pragma unroll
    for (int i = 0; i < 8; ++i) {
        float4 v = p[t + i * 256];
        s  += v.x + v.y + v.z + v.w;
        ss += v.x * v.x + v.y * v.y + v.z * v.z + v.w * v.w;
    }
#pragma unroll
    for (int off = 32; off; off >>= 1) {
        s  += __shfl_xor(s, off, 64);
        ss += __shfl_xor(ss, off, 64);
    }
    __shared__ float ls[8];
    int wave = t >> 6, lane = t & 63;
    if (lane == 0) { ls[wave * 2] = s; ls[wave * 2 + 1] = ss; }
    __syncthreads();
    if (t == 0) {
        float S = 0.f, SS = 0.f;
#pragma unroll
        for (int w = 0; w < 4; ++w) { S += ls[w * 2]; SS += ls[w * 2 + 1]; }
        part[(bg * 16 + chunk) * 2]     = S;
        part[(bg * 16 + chunk) * 2 + 1] = SS;
    }
}

// ---------------- weight convert f32 -> bf16 (Q rows pre-scaled) ----------
__global__ __launch_bounds__(256) void wcvt(const float* __restrict__ wq,
                                            const float* __restrict__ wp,
                                            ushort* __restrict__ wqb,
                                            ushort* __restrict__ wpb) {
    int i = blockIdx.x * 256 + threadIdx.x;
    if (i < 768 * 256) {
        float s = (i < 256 * 256) ? QSCALE : 1.0f;
        wqb[i] = f2bf(wq[i] * s);
    } else {
        int j = i - 768 * 256;
        wpb[j] = f2bf(wp[j]);
    }
}

// ---------------- GroupNorm + transpose:  x[b][c][n] f32 -> xnT[b][n][c] bf16
// grid (HW/64, C/64, B), 256 threads
__global__ __launch_bounds__(256) void gn_xt(const float* __restrict__ x,
                                             const float* __restrict__ gamma,
                                             const float* __restrict__ beta,
                                             const float* __restrict__ part,
                                             ushort* __restrict__ xnT) {
    __shared__ float2 affs[64];
    __shared__ __align__(16) ushort Ts[64 * 72];
    int n0 = blockIdx.x * 64;
    int c0 = blockIdx.y * 64;
    int b  = blockIdx.z;
    int t = threadIdx.x;
    if (t < 64) {
        int c = c0 + t;
        int bg = b * G_ + (c >> 5);
        float S = 0.f, SS = 0.f;
#pragma unroll
        for (int i = 0; i < 16; ++i) {
            S  += part[(bg * 16 + i) * 2];
            SS += part[(bg * 16 + i) * 2 + 1];
        }
        float mean = S * (1.f / GRP_ELEMS);
        float var  = SS * (1.f / GRP_ELEMS) - mean * mean;
        float inv  = rsqrtf(var + EPS);
        float a = inv * gamma[c];
        affs[t] = make_float2(a, beta[c] - mean * a);
    }
    __syncthreads();
    int n4 = t & 15, cr = t >> 4;
#pragma unroll
    for (int ct = 0; ct < 4; ++ct) {
        int c = cr + 16 * ct;
        float2 p = affs[c];
        float4 v = *(const float4*)(x + ((size_t)(b * C_ + c0 + c)) * HW_ + n0 + n4 * 4);
        ushort e[4];
        e[0] = f2bf(v.x * p.x + p.y); e[1] = f2bf(v.y * p.x + p.y);
        e[2] = f2bf(v.z * p.x + p.y); e[3] = f2bf(v.w * p.x + p.y);
#pragma unroll
        for (int k = 0; k < 4; ++k) {
            int n = n4 * 4 + k;
            Ts[n * 72 + (((c >> 3) ^ ((n >> 2) & 7)) << 3) + (c & 7)] = e[k];
        }
    }
    __syncthreads();
#pragma unroll
    for (int nt = 0; nt < 2; ++nt) {
        int n = (t >> 3) + 32 * nt, c8 = t & 7;
        uint4 val = *(const uint4*)&Ts[n * 72 + ((c8 ^ ((n >> 2) & 7)) << 3)];
        *(uint4*)(xnT + ((size_t)b * HW_ + n0 + n) * C_ + c0 + c8 * 8) = val;
    }
}

// ---------------- QKV GEMM (bf16 MFMA, no LDS) -----------------------------
// qkv[o][n] = sum_k Wq[o][k] xnT[n][k].  Q/K written transposed -> qt/kt[n][dh],
// V written natural -> vv[c][n].  grid (64, 6, 4), 256 thr = 4 waves x (32o x 64n)
__global__ __launch_bounds__(256) void qkv_gemm(const ushort* __restrict__ wqb,
                                                const ushort* __restrict__ xnT,
                                                ushort* __restrict__ qt,
                                                ushort* __restrict__ kt,
                                                ushort* __restrict__ vv) {
    int n0 = blockIdx.x * 64;
    int o0 = blockIdx.y * 128;
    int b  = blockIdx.z;
    int t = threadIdx.x;
    int w = t >> 6, lane = t & 63, l16 = lane & 15, lg = lane >> 4;
    const ushort* xb = xnT + ((size_t)b * HW_ + n0) * C_;
    const ushort* wrow0 = wqb + (size_t)(o0 + 32 * w + l16) * C_;
    const ushort* wrow1 = wrow0 + 16 * C_;

    f32x4 acc[2][4];
#pragma unroll
    for (int os = 0; os < 2; ++os)
#pragma unroll
        for (int u = 0; u < 4; ++u)
#pragma unroll
            for (int r = 0; r < 4; ++r) acc[os][u][r] = 0.f;

#pragma unroll 2
    for (int ks = 0; ks < 8; ++ks) {
        short8 a0 = *(const short8*)(wrow0 + 32 * ks + 8 * lg);
        short8 a1 = *(const short8*)(wrow1 + 32 * ks + 8 * lg);
#pragma unroll
        for (int u = 0; u < 4; ++u) {
            short8 bf = *(const short8*)(xb + (size_t)(16 * u + l16) * C_ + 32 * ks + 8 * lg);
            acc[0][u] = __builtin_amdgcn_mfma_f32_16x16x32_bf16(a0, bf, acc[0][u], 0, 0, 0);
            acc[1][u] = __builtin_amdgcn_mfma_f32_16x16x32_bf16(a1, bf, acc[1][u], 0, 0, 0);
        }
    }

    int z = o0 >> 8;   // 0:Q 1:K 2:V
#pragma unroll
    for (int os = 0; os < 2; ++os) {
        int o_base = o0 + 32 * w + 16 * os;
        if (z < 2) {
            int h = (o_base >> 6) & 3;
            int od0 = (o_base & 63) + 4 * lg;
            ushort* dstb = (z ? kt : qt) + ((size_t)((b << 2) | h) * HW_) * DH_;
#pragma unroll
            for (int u = 0; u < 4; ++u) {
                int n = n0 + 16 * u + l16;
                ushort4 pk;
                pk.x = f2bf(acc[os][u][0]); pk.y = f2bf(acc[os][u][1]);
                pk.z = f2bf(acc[os][u][2]); pk.w = f2bf(acc[os][u][3]);
                *(ushort4*)(dstb + (size_t)n * DH_ + od0) = pk;
            }
        } else {
            int row0 = o_base - 512 + 4 * lg;
#pragma unroll
            for (int u = 0; u < 4; ++u) {
                int n = n0 + 16 * u + l16;
#pragma unroll
                for (int r = 0; r < 4; ++r)
                    vv[((size_t)(b * C_ + row0 + r)) * HW_ + n] = f2bf(acc[os][u][r]);
            }
        }
    }
}

// ---------------- MFMA flash attention v3 ----------------------------------
// grid 1024 (XCD-swizzled): 16 bh x 64 i-tiles of 64 rows. 4 waves x 16 rows.
// K staged in LDS (dbuf, swizzled); V frags direct from global; P via LDS.
__global__ __launch_bounds__(256) void flash_attn_mfma(const ushort* __restrict__ qt,
                                                       const ushort* __restrict__ kt,
                                                       const ushort* __restrict__ vv,
                                                       ushort* __restrict__ attT) {
    __shared__ __align__(16) ushort Kb[2][64 * 64];   // [j][dh], chunks swizzled
    __shared__ __align__(16) ushort Pt[64 * 72];      // [i_local][j]

    int bid = blockIdx.x;
    int wg = (bid & 7) * 128 + (bid >> 3);   // bijective: 1024 = 8 * 128
    int bh = wg >> 6;
    int i0 = (wg & 63) * 64;
    int b = bh >> 2, h = bh & 3;
    int t = threadIdx.x;
    int w = t >> 6, lane = t & 63, l16 = lane & 15, lg = lane >> 4;
    const ushort* qtb = qt + (size_t)bh * HW_ * DH_;
    const ushort* ktb = kt + (size_t)bh * HW_ * DH_;
    const ushort* vb  = vv + ((size_t)(b * C_) + h * DH_) * HW_;

    short8 qf[2];
#pragma unroll
    for (int ks = 0; ks < 2; ++ks)
        qf[ks] = *(const short8*)(qtb + (size_t)(i0 + 16 * w + l16) * DH_ + 32 * ks + 8 * lg);

    f32x4 O[4];
#pragma unroll
    for (int dt = 0; dt < 4; ++dt)
#pragma unroll
        for (int r = 0; r < 4; ++r) O[dt][r] = 0.f;
    float m = -1e30f, l = 0.f;

    ushort* Prow = &Pt[(16 * w + l16) * 72];

    int r8 = lane >> 3, ch8 = lane & 7;
    auto stage = [&](int bi, int j0) {
#pragma unroll
        for (int half = 0; half < 2; ++half) {
            int rowb = 16 * w + half * 8;
            const ushort* srck = ktb + (size_t)(j0 + rowb + r8) * DH_ + ((ch8 ^ r8) << 3);
            __builtin_amdgcn_global_load_lds((gas1_t)srck,
                (las3_t)&Kb[bi][rowb * 64], 16, 0, 0);
        }
    };

    stage(0, 0);
    asm volatile("s_waitcnt vmcnt(0)" ::: "memory");
    __builtin_amdgcn_s_barrier();

    int cur = 0;
    for (int t8 = 0; t8 < NT_; ++t8) {
        if (t8 + 1 < NT_) stage(cur ^ 1, (t8 + 1) * 64);
        int j0 = t8 * 64;

        // ---- S^T = K · Q ---------------------------------------------------
        f32x4 S[4];
#pragma unroll
        for (int jt = 0; jt < 4; ++jt) {
#pragma unroll
            for (int r = 0; r < 4; ++r) S[jt][r] = 0.f;
#pragma unroll
            for (int ks = 0; ks < 2; ++ks) {
                short8 kf = *(const short8*)&Kb[cur][(16 * jt + l16) * 64 +
                                                     (((4 * ks + lg) ^ (l16 & 7)) << 3)];
                S[jt] = __builtin_amdgcn_mfma_f32_16x16x32_bf16(kf, qf[ks], S[jt], 0, 0, 0);
            }
        }

        // ---- V frag loads (global, L1/L2-resident) -------------------------
        short8 vf[4][2];
#pragma unroll
        for (int dt = 0; dt < 4; ++dt)
#pragma unroll
            for (int ks = 0; ks < 2; ++ks)
                vf[dt][ks] = *(const short8*)(vb + (size_t)(16 * dt + l16) * HW_ + j0 + 32 * ks + 8 * lg);

        // ---- online softmax (log2 domain, defer-max) -----------------------
        float mx = S[0][0];
#pragma unroll
        for (int jt = 0; jt < 4; ++jt)
#pragma unroll
            for (int r = 0; r < 4; ++r) mx = fmaxf(mx, S[jt][r]);
        mx = fmaxf(mx, __shfl_xor(mx, 16, 64));
        mx = fmaxf(mx, __shfl_xor(mx, 32, 64));
        if (!__all(mx <= m + 8.f)) {
            float mn = fmaxf(m, mx);
            float alpha = __builtin_amdgcn_exp2f(m - mn);
            l *= alpha;
            m = mn;
#pragma unroll
            for (int dt = 0; dt < 4; ++dt)
#pragma unroll
                for (int r = 0; r < 4; ++r) O[dt][r] *= alpha;
        }
        float rs = 0.f;
#pragma unroll
        for (int jt = 0; jt < 4; ++jt) {
            ushort4 pk;
#pragma unroll
            for (int r = 0; r < 4; ++r) {
                S[jt][r] = __builtin_amdgcn_exp2f(S[jt][r] - m);
                rs += S[jt][r];
            }
            pk.x = f2bf(S[jt][0]); pk.y = f2bf(S[jt][1]);
            pk.z = f2bf(S[jt][2]); pk.w = f2bf(S[jt][3]);
            *(ushort4*)(Prow + 16 * jt + 4 * lg) = pk;
        }
        rs += __shfl_xor(rs, 16, 64);
        rs += __shfl_xor(rs, 32, 64);
        l += rs;

        short8 pf[2];
#pragma unroll
        for (int ks = 0; ks < 2; ++ks)
            pf[ks] = *(const short8*)(Prow + 32 * ks + 8 * lg);

        // ---- O^T += V^T · P^T ----------------------------------------------
#pragma unroll
        for (int dt = 0; dt < 4; ++dt) {
            O[dt] = __builtin_amdgcn_mfma_f32_16x16x32_bf16(vf[dt][0], pf[0], O[dt], 0, 0, 0);
            O[dt] = __builtin_amdgcn_mfma_f32_16x16x32_bf16(vf[dt][1], pf[1], O[dt], 0, 0, 0);
        }

        asm volatile("s_waitcnt vmcnt(0)" ::: "memory");
        __builtin_amdgcn_s_barrier();
        cur ^= 1;
    }

    // ---- epilogue: write attT[b][n][c] bf16 -------------------------------
    float inv = 1.f / l;
    ushort* ab = attT + ((size_t)b * HW_ + i0 + 16 * w + l16) * C_ + h * DH_;
#pragma unroll
    for (int dt = 0; dt < 4; ++dt) {
        ushort4 pk;
        pk.x = f2bf(O[dt][0] * inv); pk.y = f2bf(O[dt][1] * inv);
        pk.z = f2bf(O[dt][2] * inv); pk.w = f2bf(O[dt][3] * inv);
        *(ushort4*)(ab + 16 * dt + 4 * lg) = pk;
    }
}

// ---------------- proj GEMM (bf16 MFMA) + bias + residual ------------------
// out[b][m][n] f32 = Wp[m][k] attT[n][k] + bias[m] + x[b][m][n]
__global__ __launch_bounds__(256) void proj_gemm(const ushort* __restrict__ wpb,
                                                 const ushort* __restrict__ attT,
                                                 const float* __restrict__ bias,
                                                 const float* __restrict__ x,
                                                 float* __restrict__ out) {
    int n0 = blockIdx.x * 64;
    int o0 = blockIdx.y * 128;
    int b  = blockIdx.z;
    int t = threadIdx.x;
    int w = t >> 6, lane = t & 63, l16 = lane & 15, lg = lane >> 4;
    const ushort* xb = attT + ((size_t)b * HW_ + n0) * C_;
    const ushort* wrow0 = wpb + (size_t)(o0 + 32 * w + l16) * C_;
    const ushort* wrow1 = wrow0 + 16 * C_;

    f32x4 acc[2][4];
#pragma unroll
    for (int os = 0; os < 2; ++os)
#pragma unroll
        for (int u = 0; u < 4; ++u)
#pragma unroll
            for (int r = 0; r < 4; ++r) acc[os][u][r] = 0.f;

#pragma unroll 2
    for (int ks = 0; ks < 8; ++ks) {
        short8 a0 = *(const short8*)(wrow0 + 32 * ks + 8 * lg);
        short8 a1 = *(const short8*)(wrow1 + 32 * ks + 8 * lg);
#pragma unroll
        for (int u = 0; u < 4; ++u) {
            short8 bf = *(const short8*)(xb + (size_t)(16 * u + l16) * C_ + 32 * ks + 8 * lg);
            acc[0][u] = __builtin_amdgcn_mfma_f32_16x16x32_bf16(a0, bf, acc[0][u], 0, 0, 0);
            acc[1][u] = __builtin_amdgcn_mfma_f32_16x16x32_bf16(a1, bf, acc[1][u], 0, 0, 0);
        }
    }

#pragma unroll
    for (int os = 0; os < 2; ++os) {
        int o_base = o0 + 32 * w + 16 * os;
#pragma unroll
        for (int u = 0; u < 4; ++u) {
            int n = n0 + 16 * u + l16;
#pragma unroll
            for (int r = 0; r < 4; ++r) {
                int mrow = o_base + 4 * lg + r;
                size_t idx = ((size_t)(b * C_ + mrow)) * HW_ + n;
                out[idx] = acc[os][u][r] + bias[mrow] + x[idx];
            }
        }
    }
}

extern "C" void kernel_launch(void* const* d_in, const int* in_sizes, int n_in,
                              void* d_out, int out_size, void* d_ws, size_t ws_size,
                              hipStream_t stream) {
    const float* x        = (const float*)d_in[0];
    const float* gn_gamma = (const float*)d_in[1];
    const float* gn_beta  = (const float*)d_in[2];
    const float* w_qkv    = (const float*)d_in[3];
    const float* w_proj   = (const float*)d_in[4];
    const float* b_proj   = (const float*)d_in[5];
    float* out = (float*)d_out;

    ushort* wsp  = (ushort*)d_ws;
    ushort* xnT  = wsp;                       // 4*4096*256
    ushort* qt   = xnT  + 4194304;            // 16*4096*64
    ushort* kt   = qt   + 4194304;
    ushort* vv   = kt   + 4194304;            // 4*256*4096
    ushort* attT = vv   + 4194304;            // 4*4096*256
    ushort* wqb  = attT + 4194304;            // 768*256
    ushort* wpb  = wqb  + 196608;             // 256*256
    float*  part = (float*)(wpb + 65536);     // 512 floats

    gn_partial<<<dim3(G_ * B_ * NCHUNK), 256, 0, stream>>>(x, part);
    wcvt<<<dim3(1024), 256, 0, stream>>>(w_qkv, w_proj, wqb, wpb);
    gn_xt<<<dim3(HW_ / 64, C_ / 64, B_), 256, 0, stream>>>(x, gn_gamma, gn_beta, part, xnT);
    qkv_gemm<<<dim3(HW_ / 64, 6, B_), 256, 0, stream>>>(wqb, xnT, qt, kt, vv);
    flash_attn_mfma<<<dim3(1024), 256, 0, stream>>>(qt, kt, vv, attT);
    proj_gemm<<<dim3(HW_ / 64, 2, B_), 256, 0, stream>>>(wpb, attT, b_proj, x, out);
}

// Round 6
// 194.274 us; speedup vs baseline: 2.0908x; 2.0908x over previous
//
#include <hip/hip_runtime.h>
#include <math.h>
#include <stdint.h>

#define B_ 4
#define C_ 256
#define HW_ 4096
#define G_ 8
#define H_ 4
#define DH_ 64
#define GRP_ELEMS (32 * HW_)             // 131072
#define NCHUNK 16
#define CHUNK_ELEMS (GRP_ELEMS / NCHUNK) // 8192
#define EPS 1e-5f
#define NT_ (HW_ / 64)                   // 64 j-tiles
#define QSCALE 0.04508422f               // (1/32) * log2(e)

typedef __attribute__((ext_vector_type(8))) short short8;
typedef __attribute__((ext_vector_type(4))) float f32x4;
typedef const __attribute__((address_space(1))) uint32_t* gas1_t;
typedef __attribute__((address_space(3))) uint32_t* las3_t;

__device__ __forceinline__ ushort f2bf(float x) {
    unsigned u = __builtin_bit_cast(unsigned, x);
    u += 0x7FFFu + ((u >> 16) & 1u);
    return (ushort)(u >> 16);
}
__device__ __forceinline__ uint32_t cvt_pk_bf16(float lo, float hi) {
    uint32_t r;
    asm("v_cvt_pk_bf16_f32 %0, %1, %2" : "=v"(r) : "v"(lo), "v"(hi));
    return r;
}

// ---------------- GroupNorm stage 1: deterministic partial sums -----------
__global__ __launch_bounds__(256) void gn_partial(const float* __restrict__ x,
                                                  float* __restrict__ part) {
    int bg = blockIdx.x >> 4;
    int chunk = blockIdx.x & 15;
    const float4* p = (const float4*)(x + (size_t)bg * GRP_ELEMS + (size_t)chunk * CHUNK_ELEMS);
    int t = threadIdx.x;
    float s = 0.f, ss = 0.f;
#pragma unroll
    for (int i = 0; i < 8; ++i) {
        float4 v = p[t + i * 256];
        s  += v.x + v.y + v.z + v.w;
        ss += v.x * v.x + v.y * v.y + v.z * v.z + v.w * v.w;
    }
#pragma unroll
    for (int off = 32; off; off >>= 1) {
        s  += __shfl_xor(s, off, 64);
        ss += __shfl_xor(ss, off, 64);
    }
    __shared__ float ls[8];
    int wave = t >> 6, lane = t & 63;
    if (lane == 0) { ls[wave * 2] = s; ls[wave * 2 + 1] = ss; }
    __syncthreads();
    if (t == 0) {
        float S = 0.f, SS = 0.f;
#pragma unroll
        for (int w = 0; w < 4; ++w) { S += ls[w * 2]; SS += ls[w * 2 + 1]; }
        part[(bg * 16 + chunk) * 2]     = S;
        part[(bg * 16 + chunk) * 2 + 1] = SS;
    }
}

// ---------------- weight convert f32 -> bf16 (Q rows pre-scaled) ----------
__global__ __launch_bounds__(256) void wcvt(const float* __restrict__ wq,
                                            const float* __restrict__ wp,
                                            ushort* __restrict__ wqb,
                                            ushort* __restrict__ wpb) {
    int i = blockIdx.x * 256 + threadIdx.x;
    if (i < 768 * 256) {
        float s = (i < 256 * 256) ? QSCALE : 1.0f;
        wqb[i] = f2bf(wq[i] * s);
    } else {
        int j = i - 768 * 256;
        wpb[j] = f2bf(wp[j]);
    }
}

// ---------------- GroupNorm + transpose:  x[b][c][n] f32 -> xnT[b][n][c] bf16
__global__ __launch_bounds__(256) void gn_xt(const float* __restrict__ x,
                                             const float* __restrict__ gamma,
                                             const float* __restrict__ beta,
                                             const float* __restrict__ part,
                                             ushort* __restrict__ xnT) {
    __shared__ float2 affs[64];
    __shared__ __align__(16) ushort Ts[64 * 72];
    int n0 = blockIdx.x * 64;
    int c0 = blockIdx.y * 64;
    int b  = blockIdx.z;
    int t = threadIdx.x;
    if (t < 64) {
        int c = c0 + t;
        int bg = b * G_ + (c >> 5);
        float S = 0.f, SS = 0.f;
#pragma unroll
        for (int i = 0; i < 16; ++i) {
            S  += part[(bg * 16 + i) * 2];
            SS += part[(bg * 16 + i) * 2 + 1];
        }
        float mean = S * (1.f / GRP_ELEMS);
        float var  = SS * (1.f / GRP_ELEMS) - mean * mean;
        float inv  = rsqrtf(var + EPS);
        float a = inv * gamma[c];
        affs[t] = make_float2(a, beta[c] - mean * a);
    }
    __syncthreads();
    int n4 = t & 15, cr = t >> 4;
#pragma unroll
    for (int ct = 0; ct < 4; ++ct) {
        int c = cr + 16 * ct;
        float2 p = affs[c];
        float4 v = *(const float4*)(x + ((size_t)(b * C_ + c0 + c)) * HW_ + n0 + n4 * 4);
        ushort e[4];
        e[0] = f2bf(v.x * p.x + p.y); e[1] = f2bf(v.y * p.x + p.y);
        e[2] = f2bf(v.z * p.x + p.y); e[3] = f2bf(v.w * p.x + p.y);
#pragma unroll
        for (int k = 0; k < 4; ++k) {
            int n = n4 * 4 + k;
            Ts[n * 72 + (((c >> 3) ^ ((n >> 2) & 7)) << 3) + (c & 7)] = e[k];
        }
    }
    __syncthreads();
#pragma unroll
    for (int nt = 0; nt < 2; ++nt) {
        int n = (t >> 3) + 32 * nt, c8 = t & 7;
        uint4 val = *(const uint4*)&Ts[n * 72 + ((c8 ^ ((n >> 2) & 7)) << 3)];
        *(uint4*)(xnT + ((size_t)b * HW_ + n0 + n) * C_ + c0 + c8 * 8) = val;
    }
}

// ---------------- QKV GEMM (bf16 MFMA, no LDS) -----------------------------
__global__ __launch_bounds__(256) void qkv_gemm(const ushort* __restrict__ wqb,
                                                const ushort* __restrict__ xnT,
                                                ushort* __restrict__ qt,
                                                ushort* __restrict__ kt,
                                                ushort* __restrict__ vv) {
    int n0 = blockIdx.x * 64;
    int o0 = blockIdx.y * 128;
    int b  = blockIdx.z;
    int t = threadIdx.x;
    int w = t >> 6, lane = t & 63, l16 = lane & 15, lg = lane >> 4;
    const ushort* xb = xnT + ((size_t)b * HW_ + n0) * C_;
    const ushort* wrow0 = wqb + (size_t)(o0 + 32 * w + l16) * C_;
    const ushort* wrow1 = wrow0 + 16 * C_;

    f32x4 acc[2][4];
#pragma unroll
    for (int os = 0; os < 2; ++os)
#pragma unroll
        for (int u = 0; u < 4; ++u)
#pragma unroll
            for (int r = 0; r < 4; ++r) acc[os][u][r] = 0.f;

#pragma unroll 2
    for (int ks = 0; ks < 8; ++ks) {
        short8 a0 = *(const short8*)(wrow0 + 32 * ks + 8 * lg);
        short8 a1 = *(const short8*)(wrow1 + 32 * ks + 8 * lg);
#pragma unroll
        for (int u = 0; u < 4; ++u) {
            short8 bf = *(const short8*)(xb + (size_t)(16 * u + l16) * C_ + 32 * ks + 8 * lg);
            acc[0][u] = __builtin_amdgcn_mfma_f32_16x16x32_bf16(a0, bf, acc[0][u], 0, 0, 0);
            acc[1][u] = __builtin_amdgcn_mfma_f32_16x16x32_bf16(a1, bf, acc[1][u], 0, 0, 0);
        }
    }

    int z = o0 >> 8;   // 0:Q 1:K 2:V
#pragma unroll
    for (int os = 0; os < 2; ++os) {
        int o_base = o0 + 32 * w + 16 * os;
        if (z < 2) {
            int h = (o_base >> 6) & 3;
            int od0 = (o_base & 63) + 4 * lg;
            ushort* dstb = (z ? kt : qt) + ((size_t)((b << 2) | h) * HW_) * DH_;
#pragma unroll
            for (int u = 0; u < 4; ++u) {
                int n = n0 + 16 * u + l16;
                uint2 pk;
                pk.x = cvt_pk_bf16(acc[os][u][0], acc[os][u][1]);
                pk.y = cvt_pk_bf16(acc[os][u][2], acc[os][u][3]);
                *(uint2*)(dstb + (size_t)n * DH_ + od0) = pk;
            }
        } else {
            int row0 = o_base - 512 + 4 * lg;
#pragma unroll
            for (int u = 0; u < 4; ++u) {
                int n = n0 + 16 * u + l16;
#pragma unroll
                for (int r = 0; r < 4; ++r)
                    vv[((size_t)(b * C_ + row0 + r)) * HW_ + n] = f2bf(acc[os][u][r]);
            }
        }
    }
}

// ---------------- MFMA flash attention (round-4 structure, bf16 I/O) -------
// grid 512 (XCD-swizzled): 16 bh x 32 i-tiles of 128 rows. 256 thr = 4 waves,
// each wave owns 32 Q-rows (2 strips of 16). K/V staged via global_load_lds
// (dbuf, XOR-swizzled source chunks), shared by all 4 waves.
__global__ __launch_bounds__(256) void flash_attn_mfma(const ushort* __restrict__ qt,
                                                       const ushort* __restrict__ kt,
                                                       const ushort* __restrict__ vv,
                                                       ushort* __restrict__ attT) {
    __shared__ __align__(16) ushort Kb[2][64 * 64];   // [j][dh], chunks swizzled
    __shared__ __align__(16) ushort Vb[2][64 * 64];   // [d][j],  chunks swizzled
    __shared__ __align__(16) ushort Pt[128 * 72];     // [i_local][j]

    int bid = blockIdx.x;
    int wg = (bid & 7) * 64 + (bid >> 3);   // bijective: XCD x -> wg [64x,64x+64)
    int bh = wg >> 5;                        // 2 bh per XCD
    int i0 = (wg & 31) * 128;
    int b = bh >> 2, h = bh & 3;
    int t = threadIdx.x;
    int w = t >> 6, lane = t & 63, l16 = lane & 15, lg = lane >> 4;
    const ushort* qtb = qt + (size_t)bh * HW_ * DH_;
    const ushort* ktb = kt + (size_t)bh * HW_ * DH_;
    const ushort* vb  = vv + ((size_t)(b * C_) + h * DH_) * HW_;

    short8 qf[2][2];
#pragma unroll
    for (int s = 0; s < 2; ++s)
#pragma unroll
        for (int ks = 0; ks < 2; ++ks)
            qf[s][ks] = *(const short8*)(qtb + (size_t)(i0 + 32 * w + 16 * s + l16) * DH_ + 32 * ks + 8 * lg);

    f32x4 O0[4], O1[4];
#pragma unroll
    for (int dt = 0; dt < 4; ++dt)
#pragma unroll
        for (int r = 0; r < 4; ++r) { O0[dt][r] = 0.f; O1[dt][r] = 0.f; }
    float m0v = -1e30f, l0v = 0.f, m1v = -1e30f, l1v = 0.f;

    ushort* Prow0 = &Pt[(32 * w + l16) * 72];
    ushort* Prow1 = &Pt[(32 * w + 16 + l16) * 72];

    int r8 = lane >> 3, ch8 = lane & 7;
    auto stage = [&](int bi, int j0) {
#pragma unroll
        for (int half = 0; half < 2; ++half) {
            int row = 16 * w + half * 8 + r8;
            const ushort* srck = ktb + (size_t)(j0 + row) * DH_ + ((ch8 ^ (row & 7)) << 3);
            __builtin_amdgcn_global_load_lds((gas1_t)srck,
                (las3_t)&Kb[bi][(16 * w + half * 8) * 64], 16, 0, 0);
            const ushort* srcv = vb + (size_t)row * HW_ + j0 + ((ch8 ^ (row & 7)) << 3);
            __builtin_amdgcn_global_load_lds((gas1_t)srcv,
                (las3_t)&Vb[bi][(16 * w + half * 8) * 64], 16, 0, 0);
        }
    };

    auto softmax_p = [&](f32x4* S, float& m, float& l, f32x4* O, ushort* Prow) {
        // max reduce (max3-fusable trees)
        float mxa = fmaxf(fmaxf(S[0][0], S[0][1]), fmaxf(S[0][2], S[0][3]));
        float mxb = fmaxf(fmaxf(S[1][0], S[1][1]), fmaxf(S[1][2], S[1][3]));
        float mxc = fmaxf(fmaxf(S[2][0], S[2][1]), fmaxf(S[2][2], S[2][3]));
        float mxd = fmaxf(fmaxf(S[3][0], S[3][1]), fmaxf(S[3][2], S[3][3]));
        float mx = fmaxf(fmaxf(mxa, mxb), fmaxf(mxc, mxd));
        mx = fmaxf(mx, __shfl_xor(mx, 16, 64));
        mx = fmaxf(mx, __shfl_xor(mx, 32, 64));
        if (!__all(mx <= m + 8.f)) {
            float mn = fmaxf(m, mx);
            float alpha = __builtin_amdgcn_exp2f(m - mn);
            l *= alpha;
            m = mn;
#pragma unroll
            for (int dt = 0; dt < 4; ++dt)
#pragma unroll
                for (int r = 0; r < 4; ++r) O[dt][r] *= alpha;
        }
        float rs = 0.f;
#pragma unroll
        for (int jt = 0; jt < 4; ++jt) {
#pragma unroll
            for (int r = 0; r < 4; ++r)
                S[jt][r] = __builtin_amdgcn_exp2f(S[jt][r] - m);
            rs += (S[jt][0] + S[jt][1]) + (S[jt][2] + S[jt][3]);
            uint2 pk;
            pk.x = cvt_pk_bf16(S[jt][0], S[jt][1]);
            pk.y = cvt_pk_bf16(S[jt][2], S[jt][3]);
            *(uint2*)(Prow + 16 * jt + 4 * lg) = pk;
        }
        rs += __shfl_xor(rs, 16, 64);
        rs += __shfl_xor(rs, 32, 64);
        l += rs;
    };

    stage(0, 0);
    asm volatile("s_waitcnt vmcnt(0)" ::: "memory");
    __builtin_amdgcn_s_barrier();

    int cur = 0;
    for (int t8 = 0; t8 < NT_; ++t8) {
        if (t8 + 1 < NT_) stage(cur ^ 1, (t8 + 1) * 64);

        // ---- S^T = K · Q, both strips (K frags read once) ----------------
        f32x4 S0[4], S1[4];
#pragma unroll
        for (int jt = 0; jt < 4; ++jt) {
#pragma unroll
            for (int r = 0; r < 4; ++r) { S0[jt][r] = 0.f; S1[jt][r] = 0.f; }
#pragma unroll
            for (int ks = 0; ks < 2; ++ks) {
                short8 kf = *(const short8*)&Kb[cur][(16 * jt + l16) * 64 +
                                                     (((4 * ks + lg) ^ (l16 & 7)) << 3)];
                S0[jt] = __builtin_amdgcn_mfma_f32_16x16x32_bf16(kf, qf[0][ks], S0[jt], 0, 0, 0);
                S1[jt] = __builtin_amdgcn_mfma_f32_16x16x32_bf16(kf, qf[1][ks], S1[jt], 0, 0, 0);
            }
        }

        softmax_p(S0, m0v, l0v, O0, Prow0);
        softmax_p(S1, m1v, l1v, O1, Prow1);

        short8 pf0[2], pf1[2];
#pragma unroll
        for (int ks = 0; ks < 2; ++ks) {
            pf0[ks] = *(const short8*)(Prow0 + 32 * ks + 8 * lg);
            pf1[ks] = *(const short8*)(Prow1 + 32 * ks + 8 * lg);
        }

        // ---- O^T += V^T · P^T, both strips (V frags read once) ------------
#pragma unroll
        for (int dt = 0; dt < 4; ++dt) {
#pragma unroll
            for (int ks = 0; ks < 2; ++ks) {
                short8 vf = *(const short8*)&Vb[cur][(16 * dt + l16) * 64 +
                                                     (((4 * ks + lg) ^ (l16 & 7)) << 3)];
                O0[dt] = __builtin_amdgcn_mfma_f32_16x16x32_bf16(vf, pf0[ks], O0[dt], 0, 0, 0);
                O1[dt] = __builtin_amdgcn_mfma_f32_16x16x32_bf16(vf, pf1[ks], O1[dt], 0, 0, 0);
            }
        }

        asm volatile("s_waitcnt vmcnt(0)" ::: "memory");
        __builtin_amdgcn_s_barrier();
        cur ^= 1;
    }

    // ---- epilogue: write attT[b][n][c] bf16 -------------------------------
    float inv0 = 1.f / l0v, inv1 = 1.f / l1v;
    ushort* ab0 = attT + ((size_t)b * HW_ + i0 + 32 * w + l16) * C_ + h * DH_;
    ushort* ab1 = ab0 + 16 * C_;
#pragma unroll
    for (int dt = 0; dt < 4; ++dt) {
        uint2 p0, p1;
        p0.x = cvt_pk_bf16(O0[dt][0] * inv0, O0[dt][1] * inv0);
        p0.y = cvt_pk_bf16(O0[dt][2] * inv0, O0[dt][3] * inv0);
        *(uint2*)(ab0 + 16 * dt + 4 * lg) = p0;
        p1.x = cvt_pk_bf16(O1[dt][0] * inv1, O1[dt][1] * inv1);
        p1.y = cvt_pk_bf16(O1[dt][2] * inv1, O1[dt][3] * inv1);
        *(uint2*)(ab1 + 16 * dt + 4 * lg) = p1;
    }
}

// ---------------- proj GEMM (bf16 MFMA) + bias + residual ------------------
__global__ __launch_bounds__(256) void proj_gemm(const ushort* __restrict__ wpb,
                                                 const ushort* __restrict__ attT,
                                                 const float* __restrict__ bias,
                                                 const float* __restrict__ x,
                                                 float* __restrict__ out) {
    int n0 = blockIdx.x * 64;
    int o0 = blockIdx.y * 128;
    int b  = blockIdx.z;
    int t = threadIdx.x;
    int w = t >> 6, lane = t & 63, l16 = lane & 15, lg = lane >> 4;
    const ushort* xb = attT + ((size_t)b * HW_ + n0) * C_;
    const ushort* wrow0 = wpb + (size_t)(o0 + 32 * w + l16) * C_;
    const ushort* wrow1 = wrow0 + 16 * C_;

    f32x4 acc[2][4];
#pragma unroll
    for (int os = 0; os < 2; ++os)
#pragma unroll
        for (int u = 0; u < 4; ++u)
#pragma unroll
            for (int r = 0; r < 4; ++r) acc[os][u][r] = 0.f;

#pragma unroll 2
    for (int ks = 0; ks < 8; ++ks) {
        short8 a0 = *(const short8*)(wrow0 + 32 * ks + 8 * lg);
        short8 a1 = *(const short8*)(wrow1 + 32 * ks + 8 * lg);
#pragma unroll
        for (int u = 0; u < 4; ++u) {
            short8 bf = *(const short8*)(xb + (size_t)(16 * u + l16) * C_ + 32 * ks + 8 * lg);
            acc[0][u] = __builtin_amdgcn_mfma_f32_16x16x32_bf16(a0, bf, acc[0][u], 0, 0, 0);
            acc[1][u] = __builtin_amdgcn_mfma_f32_16x16x32_bf16(a1, bf, acc[1][u], 0, 0, 0);
        }
    }

#pragma unroll
    for (int os = 0; os < 2; ++os) {
        int o_base = o0 + 32 * w + 16 * os;
#pragma unroll
        for (int u = 0; u < 4; ++u) {
            int n = n0 + 16 * u + l16;
#pragma unroll
            for (int r = 0; r < 4; ++r) {
                int mrow = o_base + 4 * lg + r;
                size_t idx = ((size_t)(b * C_ + mrow)) * HW_ + n;
                out[idx] = acc[os][u][r] + bias[mrow] + x[idx];
            }
        }
    }
}

extern "C" void kernel_launch(void* const* d_in, const int* in_sizes, int n_in,
                              void* d_out, int out_size, void* d_ws, size_t ws_size,
                              hipStream_t stream) {
    const float* x        = (const float*)d_in[0];
    const float* gn_gamma = (const float*)d_in[1];
    const float* gn_beta  = (const float*)d_in[2];
    const float* w_qkv    = (const float*)d_in[3];
    const float* w_proj   = (const float*)d_in[4];
    const float* b_proj   = (const float*)d_in[5];
    float* out = (float*)d_out;

    ushort* wsp  = (ushort*)d_ws;
    ushort* xnT  = wsp;                       // 4*4096*256
    ushort* qt   = xnT  + 4194304;            // 16*4096*64
    ushort* kt   = qt   + 4194304;
    ushort* vv   = kt   + 4194304;            // 4*256*4096
    ushort* attT = vv   + 4194304;            // 4*4096*256
    ushort* wqb  = attT + 4194304;            // 768*256
    ushort* wpb  = wqb  + 196608;             // 256*256
    float*  part = (float*)(wpb + 65536);     // 512 floats

    gn_partial<<<dim3(G_ * B_ * NCHUNK), 256, 0, stream>>>(x, part);
    wcvt<<<dim3(1024), 256, 0, stream>>>(w_qkv, w_proj, wqb, wpb);
    gn_xt<<<dim3(HW_ / 64, C_ / 64, B_), 256, 0, stream>>>(x, gn_gamma, gn_beta, part, xnT);
    qkv_gemm<<<dim3(HW_ / 64, 6, B_), 256, 0, stream>>>(wqb, xnT, qt, kt, vv);
    flash_attn_mfma<<<dim3(512), 256, 0, stream>>>(qt, kt, vv, attT);
    proj_gemm<<<dim3(HW_ / 64, 2, B_), 256, 0, stream>>>(wpb, attT, b_proj, x, out);
}

// Round 7
// 184.732 us; speedup vs baseline: 2.1988x; 1.0517x over previous
//
#include <hip/hip_runtime.h>
#include <math.h>
#include <stdint.h>

#define B_ 4
#define C_ 256
#define HW_ 4096
#define G_ 8
#define H_ 4
#define DH_ 64
#define GRP_ELEMS (32 * HW_)             // 131072
#define NCHUNK 16
#define CHUNK_ELEMS (GRP_ELEMS / NCHUNK) // 8192
#define EPS 1e-5f
#define NT_ (HW_ / 64)                   // 64 j-tiles
#define QSCALE 0.04508422f               // (1/32) * log2(e)

typedef __attribute__((ext_vector_type(8))) short short8;
typedef __attribute__((ext_vector_type(4))) float f32x4;
typedef __attribute__((ext_vector_type(4))) unsigned int u32x4;
typedef const __attribute__((address_space(1))) uint32_t* gas1_t;
typedef __attribute__((address_space(3))) uint32_t* las3_t;

__device__ __forceinline__ ushort f2bf(float x) {
    unsigned u = __builtin_bit_cast(unsigned, x);
    u += 0x7FFFu + ((u >> 16) & 1u);
    return (ushort)(u >> 16);
}
__device__ __forceinline__ uint32_t cvt_pk_bf16(float lo, float hi) {
    uint32_t r;
    asm("v_cvt_pk_bf16_f32 %0, %1, %2" : "=v"(r) : "v"(lo), "v"(hi));
    return r;
}

// ---------------- GroupNorm stage 1: deterministic partial sums -----------
__global__ __launch_bounds__(256) void gn_partial(const float* __restrict__ x,
                                                  float* __restrict__ part) {
    int bg = blockIdx.x >> 4;
    int chunk = blockIdx.x & 15;
    const float4* p = (const float4*)(x + (size_t)bg * GRP_ELEMS + (size_t)chunk * CHUNK_ELEMS);
    int t = threadIdx.x;
    float s = 0.f, ss = 0.f;
#pragma unroll
    for (int i = 0; i < 8; ++i) {
        float4 v = p[t + i * 256];
        s  += v.x + v.y + v.z + v.w;
        ss += v.x * v.x + v.y * v.y + v.z * v.z + v.w * v.w;
    }
#pragma unroll
    for (int off = 32; off; off >>= 1) {
        s  += __shfl_xor(s, off, 64);
        ss += __shfl_xor(ss, off, 64);
    }
    __shared__ float ls[8];
    int wave = t >> 6, lane = t & 63;
    if (lane == 0) { ls[wave * 2] = s; ls[wave * 2 + 1] = ss; }
    __syncthreads();
    if (t == 0) {
        float S = 0.f, SS = 0.f;
#pragma unroll
        for (int w = 0; w < 4; ++w) { S += ls[w * 2]; SS += ls[w * 2 + 1]; }
        part[(bg * 16 + chunk) * 2]     = S;
        part[(bg * 16 + chunk) * 2 + 1] = SS;
    }
}

// ---------------- weight convert f32 -> bf16 (Q rows pre-scaled) ----------
__global__ __launch_bounds__(256) void wcvt(const float* __restrict__ wq,
                                            const float* __restrict__ wp,
                                            ushort* __restrict__ wqb,
                                            ushort* __restrict__ wpb) {
    int i = blockIdx.x * 256 + threadIdx.x;
    if (i < 768 * 256) {
        float s = (i < 256 * 256) ? QSCALE : 1.0f;
        wqb[i] = f2bf(wq[i] * s);
    } else {
        int j = i - 768 * 256;
        wpb[j] = f2bf(wp[j]);
    }
}

// ---------------- GroupNorm + transpose:  x[b][c][n] f32 -> xnT[b][n][c] bf16
__global__ __launch_bounds__(256) void gn_xt(const float* __restrict__ x,
                                             const float* __restrict__ gamma,
                                             const float* __restrict__ beta,
                                             const float* __restrict__ part,
                                             ushort* __restrict__ xnT) {
    __shared__ float2 affs[64];
    __shared__ __align__(16) ushort Ts[64 * 72];
    int n0 = blockIdx.x * 64;
    int c0 = blockIdx.y * 64;
    int b  = blockIdx.z;
    int t = threadIdx.x;
    if (t < 64) {
        int c = c0 + t;
        int bg = b * G_ + (c >> 5);
        float S = 0.f, SS = 0.f;
#pragma unroll
        for (int i = 0; i < 16; ++i) {
            S  += part[(bg * 16 + i) * 2];
            SS += part[(bg * 16 + i) * 2 + 1];
        }
        float mean = S * (1.f / GRP_ELEMS);
        float var  = SS * (1.f / GRP_ELEMS) - mean * mean;
        float inv  = rsqrtf(var + EPS);
        float a = inv * gamma[c];
        affs[t] = make_float2(a, beta[c] - mean * a);
    }
    __syncthreads();
    int n4 = t & 15, cr = t >> 4;
#pragma unroll
    for (int ct = 0; ct < 4; ++ct) {
        int c = cr + 16 * ct;
        float2 p = affs[c];
        float4 v = *(const float4*)(x + ((size_t)(b * C_ + c0 + c)) * HW_ + n0 + n4 * 4);
        ushort e[4];
        e[0] = f2bf(v.x * p.x + p.y); e[1] = f2bf(v.y * p.x + p.y);
        e[2] = f2bf(v.z * p.x + p.y); e[3] = f2bf(v.w * p.x + p.y);
#pragma unroll
        for (int k = 0; k < 4; ++k) {
            int n = n4 * 4 + k;
            Ts[n * 72 + (((c >> 3) ^ ((n >> 2) & 7)) << 3) + (c & 7)] = e[k];
        }
    }
    __syncthreads();
#pragma unroll
    for (int nt = 0; nt < 2; ++nt) {
        int n = (t >> 3) + 32 * nt, c8 = t & 7;
        uint4 val = *(const uint4*)&Ts[n * 72 + ((c8 ^ ((n >> 2) & 7)) << 3)];
        *(uint4*)(xnT + ((size_t)b * HW_ + n0 + n) * C_ + c0 + c8 * 8) = val;
    }
}

// ---------------- QKV GEMM (bf16 MFMA, no LDS) -----------------------------
__global__ __launch_bounds__(256) void qkv_gemm(const ushort* __restrict__ wqb,
                                                const ushort* __restrict__ xnT,
                                                ushort* __restrict__ qt,
                                                ushort* __restrict__ kt,
                                                ushort* __restrict__ vv) {
    int n0 = blockIdx.x * 64;
    int o0 = blockIdx.y * 128;
    int b  = blockIdx.z;
    int t = threadIdx.x;
    int w = t >> 6, lane = t & 63, l16 = lane & 15, lg = lane >> 4;
    const ushort* xb = xnT + ((size_t)b * HW_ + n0) * C_;
    const ushort* wrow0 = wqb + (size_t)(o0 + 32 * w + l16) * C_;
    const ushort* wrow1 = wrow0 + 16 * C_;

    f32x4 acc[2][4];
#pragma unroll
    for (int os = 0; os < 2; ++os)
#pragma unroll
        for (int u = 0; u < 4; ++u)
#pragma unroll
            for (int r = 0; r < 4; ++r) acc[os][u][r] = 0.f;

#pragma unroll 2
    for (int ks = 0; ks < 8; ++ks) {
        short8 a0 = *(const short8*)(wrow0 + 32 * ks + 8 * lg);
        short8 a1 = *(const short8*)(wrow1 + 32 * ks + 8 * lg);
#pragma unroll
        for (int u = 0; u < 4; ++u) {
            short8 bf = *(const short8*)(xb + (size_t)(16 * u + l16) * C_ + 32 * ks + 8 * lg);
            acc[0][u] = __builtin_amdgcn_mfma_f32_16x16x32_bf16(a0, bf, acc[0][u], 0, 0, 0);
            acc[1][u] = __builtin_amdgcn_mfma_f32_16x16x32_bf16(a1, bf, acc[1][u], 0, 0, 0);
        }
    }

    int z = o0 >> 8;   // 0:Q 1:K 2:V
#pragma unroll
    for (int os = 0; os < 2; ++os) {
        int o_base = o0 + 32 * w + 16 * os;
        if (z < 2) {
            int h = (o_base >> 6) & 3;
            int od0 = (o_base & 63) + 4 * lg;
            ushort* dstb = (z ? kt : qt) + ((size_t)((b << 2) | h) * HW_) * DH_;
#pragma unroll
            for (int u = 0; u < 4; ++u) {
                int n = n0 + 16 * u + l16;
                uint2 pk;
                pk.x = cvt_pk_bf16(acc[os][u][0], acc[os][u][1]);
                pk.y = cvt_pk_bf16(acc[os][u][2], acc[os][u][3]);
                *(uint2*)(dstb + (size_t)n * DH_ + od0) = pk;
            }
        } else {
            int row0 = o_base - 512 + 4 * lg;
#pragma unroll
            for (int u = 0; u < 4; ++u) {
                int n = n0 + 16 * u + l16;
#pragma unroll
                for (int r = 0; r < 4; ++r)
                    vv[((size_t)(b * C_ + row0 + r)) * HW_ + n] = f2bf(acc[os][u][r]);
            }
        }
    }
}

// ---------------- MFMA flash attention, register-P ------------------------
// grid 512 (XCD-swizzled): 16 bh x 32 i-tiles of 128 rows. 4 waves x 2 strips.
// K staged with row permutation g(L) so the PV B-frag is lane-local cvt_pk of
// S registers (no P LDS round-trip). V staged naturally. K/V dbuf, swizzled.
__global__ __launch_bounds__(256) void flash_attn_mfma(const ushort* __restrict__ qt,
                                                       const ushort* __restrict__ kt,
                                                       const ushort* __restrict__ vv,
                                                       ushort* __restrict__ attT) {
    __shared__ __align__(16) ushort Kb[2][64 * 64];   // [row perm][dh], chunks swz
    __shared__ __align__(16) ushort Vb[2][64 * 64];   // [d][j],  chunks swz

    int bid = blockIdx.x;
    int wg = (bid & 7) * 64 + (bid >> 3);   // bijective: XCD x -> wg [64x,64x+64)
    int bh = wg >> 5;                        // 2 bh per XCD
    int i0 = (wg & 31) * 128;
    int b = bh >> 2, h = bh & 3;
    int t = threadIdx.x;
    int w = t >> 6, lane = t & 63, l16 = lane & 15, lg = lane >> 4;
    const ushort* qtb = qt + (size_t)bh * HW_ * DH_;
    const ushort* ktb = kt + (size_t)bh * HW_ * DH_;
    const ushort* vb  = vv + ((size_t)(b * C_) + h * DH_) * HW_;

    short8 qf[2][2];
#pragma unroll
    for (int s = 0; s < 2; ++s)
#pragma unroll
        for (int ks = 0; ks < 2; ++ks)
            qf[s][ks] = *(const short8*)(qtb + (size_t)(i0 + 32 * w + 16 * s + l16) * DH_ + 32 * ks + 8 * lg);

    f32x4 O0[4], O1[4];
#pragma unroll
    for (int dt = 0; dt < 4; ++dt)
#pragma unroll
        for (int r = 0; r < 4; ++r) { O0[dt][r] = 0.f; O1[dt][r] = 0.f; }
    float m0v = -1e30f, l0v = 0.f, m1v = -1e30f, l1v = 0.f;

    // per-lane constant staging offsets (K uses row-permutation g(L))
    int r8 = lane >> 3, ch8 = lane & 7;
    size_t koff[2], voff[2];
#pragma unroll
    for (int half = 0; half < 2; ++half) {
        int L = 16 * w + half * 8 + r8;                          // K LDS row
        int gk = (L & 0x23) | ((L & 0x0C) << 1) | ((L & 0x10) >> 2); // src row
        koff[half] = (size_t)gk * DH_ + ((ch8 ^ (L & 7)) << 3);
        voff[half] = (size_t)L * HW_ + ((ch8 ^ (L & 7)) << 3);   // V natural
    }

    auto stage = [&](int bi, int j0) {
#pragma unroll
        for (int half = 0; half < 2; ++half) {
            int rowb = 16 * w + half * 8;
            __builtin_amdgcn_global_load_lds((gas1_t)(ktb + (size_t)j0 * DH_ + koff[half]),
                (las3_t)&Kb[bi][rowb * 64], 16, 0, 0);
            __builtin_amdgcn_global_load_lds((gas1_t)(vb + (size_t)j0 + voff[half]),
                (las3_t)&Vb[bi][rowb * 64], 16, 0, 0);
        }
    };

    // softmax + in-register P-frag build (defer-max, per-lane partial l)
    auto softmax_pf = [&](f32x4* S, float& m, float& l, f32x4* O, short8* pf) {
        float mxa = fmaxf(fmaxf(S[0][0], S[0][1]), fmaxf(S[0][2], S[0][3]));
        float mxb = fmaxf(fmaxf(S[1][0], S[1][1]), fmaxf(S[1][2], S[1][3]));
        float mxc = fmaxf(fmaxf(S[2][0], S[2][1]), fmaxf(S[2][2], S[2][3]));
        float mxd = fmaxf(fmaxf(S[3][0], S[3][1]), fmaxf(S[3][2], S[3][3]));
        float mx = fmaxf(fmaxf(mxa, mxb), fmaxf(mxc, mxd));
        mx = fmaxf(mx, __shfl_xor(mx, 16, 64));
        mx = fmaxf(mx, __shfl_xor(mx, 32, 64));
        if (!__all(mx <= m + 8.f)) {
            float mn = fmaxf(m, mx);
            float alpha = __builtin_amdgcn_exp2f(m - mn);
            l *= alpha;
            m = mn;
#pragma unroll
            for (int dt = 0; dt < 4; ++dt)
#pragma unroll
                for (int r = 0; r < 4; ++r) O[dt][r] *= alpha;
        }
        float rs = 0.f;
#pragma unroll
        for (int jt = 0; jt < 4; ++jt) {
#pragma unroll
            for (int r = 0; r < 4; ++r)
                S[jt][r] = __builtin_amdgcn_exp2f(S[jt][r] - m);
            rs += (S[jt][0] + S[jt][1]) + (S[jt][2] + S[jt][3]);
        }
        l += rs;                                  // per-lane partial
#pragma unroll
        for (int ks = 0; ks < 2; ++ks) {
            u32x4 p;
            p[0] = cvt_pk_bf16(S[2 * ks][0],     S[2 * ks][1]);
            p[1] = cvt_pk_bf16(S[2 * ks][2],     S[2 * ks][3]);
            p[2] = cvt_pk_bf16(S[2 * ks + 1][0], S[2 * ks + 1][1]);
            p[3] = cvt_pk_bf16(S[2 * ks + 1][2], S[2 * ks + 1][3]);
            pf[ks] = __builtin_bit_cast(short8, p);
        }
    };

    stage(0, 0);
    asm volatile("s_waitcnt vmcnt(0)" ::: "memory");
    __builtin_amdgcn_s_barrier();

    int cur = 0;
    for (int t8 = 0; t8 < NT_; ++t8) {
        if (t8 + 1 < NT_) stage(cur ^ 1, (t8 + 1) * 64);

        // ---- S^T = K · Q, both strips (K frags read once) ----------------
        f32x4 S0[4], S1[4];
#pragma unroll
        for (int jt = 0; jt < 4; ++jt) {
#pragma unroll
            for (int r = 0; r < 4; ++r) { S0[jt][r] = 0.f; S1[jt][r] = 0.f; }
#pragma unroll
            for (int ks = 0; ks < 2; ++ks) {
                short8 kf = *(const short8*)&Kb[cur][(16 * jt + l16) * 64 +
                                                     (((4 * ks + lg) ^ (l16 & 7)) << 3)];
                S0[jt] = __builtin_amdgcn_mfma_f32_16x16x32_bf16(kf, qf[0][ks], S0[jt], 0, 0, 0);
                S1[jt] = __builtin_amdgcn_mfma_f32_16x16x32_bf16(kf, qf[1][ks], S1[jt], 0, 0, 0);
            }
        }

        short8 pf0[2], pf1[2];
        softmax_pf(S0, m0v, l0v, O0, pf0);

        // ---- O0 += V^T · P0 (overlaps softmax of strip 1) ------------------
#pragma unroll
        for (int dt = 0; dt < 4; ++dt) {
#pragma unroll
            for (int ks = 0; ks < 2; ++ks) {
                short8 vf = *(const short8*)&Vb[cur][(16 * dt + l16) * 64 +
                                                     (((4 * ks + lg) ^ (l16 & 7)) << 3)];
                O0[dt] = __builtin_amdgcn_mfma_f32_16x16x32_bf16(vf, pf0[ks], O0[dt], 0, 0, 0);
            }
        }

        softmax_pf(S1, m1v, l1v, O1, pf1);
#pragma unroll
        for (int dt = 0; dt < 4; ++dt) {
#pragma unroll
            for (int ks = 0; ks < 2; ++ks) {
                short8 vf = *(const short8*)&Vb[cur][(16 * dt + l16) * 64 +
                                                     (((4 * ks + lg) ^ (l16 & 7)) << 3)];
                O1[dt] = __builtin_amdgcn_mfma_f32_16x16x32_bf16(vf, pf1[ks], O1[dt], 0, 0, 0);
            }
        }

        asm volatile("s_waitcnt vmcnt(0)" ::: "memory");
        __builtin_amdgcn_s_barrier();
        cur ^= 1;
    }

    // ---- epilogue: reduce per-lane l across lg groups, write attT bf16 ----
    l0v += __shfl_xor(l0v, 16, 64);
    l0v += __shfl_xor(l0v, 32, 64);
    l1v += __shfl_xor(l1v, 16, 64);
    l1v += __shfl_xor(l1v, 32, 64);
    float inv0 = 1.f / l0v, inv1 = 1.f / l1v;
    ushort* ab0 = attT + ((size_t)b * HW_ + i0 + 32 * w + l16) * C_ + h * DH_;
    ushort* ab1 = ab0 + 16 * C_;
#pragma unroll
    for (int dt = 0; dt < 4; ++dt) {
        uint2 p0, p1;
        p0.x = cvt_pk_bf16(O0[dt][0] * inv0, O0[dt][1] * inv0);
        p0.y = cvt_pk_bf16(O0[dt][2] * inv0, O0[dt][3] * inv0);
        *(uint2*)(ab0 + 16 * dt + 4 * lg) = p0;
        p1.x = cvt_pk_bf16(O1[dt][0] * inv1, O1[dt][1] * inv1);
        p1.y = cvt_pk_bf16(O1[dt][2] * inv1, O1[dt][3] * inv1);
        *(uint2*)(ab1 + 16 * dt + 4 * lg) = p1;
    }
}

// ---------------- proj GEMM (bf16 MFMA) + bias + residual ------------------
__global__ __launch_bounds__(256) void proj_gemm(const ushort* __restrict__ wpb,
                                                 const ushort* __restrict__ attT,
                                                 const float* __restrict__ bias,
                                                 const float* __restrict__ x,
                                                 float* __restrict__ out) {
    int n0 = blockIdx.x * 64;
    int o0 = blockIdx.y * 128;
    int b  = blockIdx.z;
    int t = threadIdx.x;
    int w = t >> 6, lane = t & 63, l16 = lane & 15, lg = lane >> 4;
    const ushort* xb = attT + ((size_t)b * HW_ + n0) * C_;
    const ushort* wrow0 = wpb + (size_t)(o0 + 32 * w + l16) * C_;
    const ushort* wrow1 = wrow0 + 16 * C_;

    f32x4 acc[2][4];
#pragma unroll
    for (int os = 0; os < 2; ++os)
#pragma unroll
        for (int u = 0; u < 4; ++u)
#pragma unroll
            for (int r = 0; r < 4; ++r) acc[os][u][r] = 0.f;

#pragma unroll 2
    for (int ks = 0; ks < 8; ++ks) {
        short8 a0 = *(const short8*)(wrow0 + 32 * ks + 8 * lg);
        short8 a1 = *(const short8*)(wrow1 + 32 * ks + 8 * lg);
#pragma unroll
        for (int u = 0; u < 4; ++u) {
            short8 bf = *(const short8*)(xb + (size_t)(16 * u + l16) * C_ + 32 * ks + 8 * lg);
            acc[0][u] = __builtin_amdgcn_mfma_f32_16x16x32_bf16(a0, bf, acc[0][u], 0, 0, 0);
            acc[1][u] = __builtin_amdgcn_mfma_f32_16x16x32_bf16(a1, bf, acc[1][u], 0, 0, 0);
        }
    }

#pragma unroll
    for (int os = 0; os < 2; ++os) {
        int o_base = o0 + 32 * w + 16 * os;
#pragma unroll
        for (int u = 0; u < 4; ++u) {
            int n = n0 + 16 * u + l16;
#pragma unroll
            for (int r = 0; r < 4; ++r) {
                int mrow = o_base + 4 * lg + r;
                size_t idx = ((size_t)(b * C_ + mrow)) * HW_ + n;
                out[idx] = acc[os][u][r] + bias[mrow] + x[idx];
            }
        }
    }
}

extern "C" void kernel_launch(void* const* d_in, const int* in_sizes, int n_in,
                              void* d_out, int out_size, void* d_ws, size_t ws_size,
                              hipStream_t stream) {
    const float* x        = (const float*)d_in[0];
    const float* gn_gamma = (const float*)d_in[1];
    const float* gn_beta  = (const float*)d_in[2];
    const float* w_qkv    = (const float*)d_in[3];
    const float* w_proj   = (const float*)d_in[4];
    const float* b_proj   = (const float*)d_in[5];
    float* out = (float*)d_out;

    ushort* wsp  = (ushort*)d_ws;
    ushort* xnT  = wsp;                       // 4*4096*256
    ushort* qt   = xnT  + 4194304;            // 16*4096*64
    ushort* kt   = qt   + 4194304;
    ushort* vv   = kt   + 4194304;            // 4*256*4096
    ushort* attT = vv   + 4194304;            // 4*4096*256
    ushort* wqb  = attT + 4194304;            // 768*256
    ushort* wpb  = wqb  + 196608;             // 256*256
    float*  part = (float*)(wpb + 65536);     // 512 floats

    gn_partial<<<dim3(G_ * B_ * NCHUNK), 256, 0, stream>>>(x, part);
    wcvt<<<dim3(1024), 256, 0, stream>>>(w_qkv, w_proj, wqb, wpb);
    gn_xt<<<dim3(HW_ / 64, C_ / 64, B_), 256, 0, stream>>>(x, gn_gamma, gn_beta, part, xnT);
    qkv_gemm<<<dim3(HW_ / 64, 6, B_), 256, 0, stream>>>(wqb, xnT, qt, kt, vv);
    flash_attn_mfma<<<dim3(512), 256, 0, stream>>>(qt, kt, vv, attT);
    proj_gemm<<<dim3(HW_ / 64, 2, B_), 256, 0, stream>>>(wpb, attT, b_proj, x, out);
}

// Round 8
// 168.541 us; speedup vs baseline: 2.4100x; 1.0961x over previous
//
#include <hip/hip_runtime.h>
#include <math.h>
#include <stdint.h>

#define B_ 4
#define C_ 256
#define HW_ 4096
#define G_ 8
#define H_ 4
#define DH_ 64
#define GRP_ELEMS (32 * HW_)             // 131072
#define NCHUNK 16
#define CHUNK_ELEMS (GRP_ELEMS / NCHUNK) // 8192
#define EPS 1e-5f
#define NT_ (HW_ / 64)                   // 64 j-tiles
#define QSCALE 0.04508422f               // (1/32) * log2(e)

typedef __attribute__((ext_vector_type(8))) short short8;
typedef __attribute__((ext_vector_type(4))) float f32x4;
typedef __attribute__((ext_vector_type(4))) unsigned int u32x4;
typedef const __attribute__((address_space(1))) uint32_t* gas1_t;
typedef __attribute__((address_space(3))) uint32_t* las3_t;

__device__ __forceinline__ ushort f2bf(float x) {
    unsigned u = __builtin_bit_cast(unsigned, x);
    u += 0x7FFFu + ((u >> 16) & 1u);
    return (ushort)(u >> 16);
}
__device__ __forceinline__ uint32_t cvt_pk_bf16(float lo, float hi) {
    uint32_t r;
    asm("v_cvt_pk_bf16_f32 %0, %1, %2" : "=v"(r) : "v"(lo), "v"(hi));
    return r;
}

// ---------------- GroupNorm stage 1: deterministic partial sums -----------
__global__ __launch_bounds__(256) void gn_partial(const float* __restrict__ x,
                                                  float* __restrict__ part) {
    int bg = blockIdx.x >> 4;
    int chunk = blockIdx.x & 15;
    const float4* p = (const float4*)(x + (size_t)bg * GRP_ELEMS + (size_t)chunk * CHUNK_ELEMS);
    int t = threadIdx.x;
    float s = 0.f, ss = 0.f;
#pragma unroll
    for (int i = 0; i < 8; ++i) {
        float4 v = p[t + i * 256];
        s  += v.x + v.y + v.z + v.w;
        ss += v.x * v.x + v.y * v.y + v.z * v.z + v.w * v.w;
    }
#pragma unroll
    for (int off = 32; off; off >>= 1) {
        s  += __shfl_xor(s, off, 64);
        ss += __shfl_xor(ss, off, 64);
    }
    __shared__ float ls[8];
    int wave = t >> 6, lane = t & 63;
    if (lane == 0) { ls[wave * 2] = s; ls[wave * 2 + 1] = ss; }
    __syncthreads();
    if (t == 0) {
        float S = 0.f, SS = 0.f;
#pragma unroll
        for (int w = 0; w < 4; ++w) { S += ls[w * 2]; SS += ls[w * 2 + 1]; }
        part[(bg * 16 + chunk) * 2]     = S;
        part[(bg * 16 + chunk) * 2 + 1] = SS;
    }
}

// ---------------- weight convert f32 -> bf16 (Q rows pre-scaled) ----------
__global__ __launch_bounds__(256) void wcvt(const float* __restrict__ wq,
                                            const float* __restrict__ wp,
                                            ushort* __restrict__ wqb,
                                            ushort* __restrict__ wpb) {
    int i = blockIdx.x * 256 + threadIdx.x;
    if (i < 768 * 256) {
        float s = (i < 256 * 256) ? QSCALE : 1.0f;
        wqb[i] = f2bf(wq[i] * s);
    } else {
        int j = i - 768 * 256;
        wpb[j] = f2bf(wp[j]);
    }
}

// ---------------- GroupNorm + transpose:  x[b][c][n] f32 -> xnT[b][n][c] bf16
__global__ __launch_bounds__(256) void gn_xt(const float* __restrict__ x,
                                             const float* __restrict__ gamma,
                                             const float* __restrict__ beta,
                                             const float* __restrict__ part,
                                             ushort* __restrict__ xnT) {
    __shared__ float2 affs[64];
    __shared__ __align__(16) ushort Ts[64 * 72];
    int n0 = blockIdx.x * 64;
    int c0 = blockIdx.y * 64;
    int b  = blockIdx.z;
    int t = threadIdx.x;
    if (t < 64) {
        int c = c0 + t;
        int bg = b * G_ + (c >> 5);
        float S = 0.f, SS = 0.f;
#pragma unroll
        for (int i = 0; i < 16; ++i) {
            S  += part[(bg * 16 + i) * 2];
            SS += part[(bg * 16 + i) * 2 + 1];
        }
        float mean = S * (1.f / GRP_ELEMS);
        float var  = SS * (1.f / GRP_ELEMS) - mean * mean;
        float inv  = rsqrtf(var + EPS);
        float a = inv * gamma[c];
        affs[t] = make_float2(a, beta[c] - mean * a);
    }
    __syncthreads();
    int n4 = t & 15, cr = t >> 4;
#pragma unroll
    for (int ct = 0; ct < 4; ++ct) {
        int c = cr + 16 * ct;
        float2 p = affs[c];
        float4 v = *(const float4*)(x + ((size_t)(b * C_ + c0 + c)) * HW_ + n0 + n4 * 4);
        ushort e[4];
        e[0] = f2bf(v.x * p.x + p.y); e[1] = f2bf(v.y * p.x + p.y);
        e[2] = f2bf(v.z * p.x + p.y); e[3] = f2bf(v.w * p.x + p.y);
#pragma unroll
        for (int k = 0; k < 4; ++k) {
            int n = n4 * 4 + k;
            Ts[n * 72 + (((c >> 3) ^ ((n >> 2) & 7)) << 3) + (c & 7)] = e[k];
        }
    }
    __syncthreads();
#pragma unroll
    for (int nt = 0; nt < 2; ++nt) {
        int n = (t >> 3) + 32 * nt, c8 = t & 7;
        uint4 val = *(const uint4*)&Ts[n * 72 + ((c8 ^ ((n >> 2) & 7)) << 3)];
        *(uint4*)(xnT + ((size_t)b * HW_ + n0 + n) * C_ + c0 + c8 * 8) = val;
    }
}

// ---------------- QKV GEMM (bf16 MFMA, no LDS) -----------------------------
__global__ __launch_bounds__(256) void qkv_gemm(const ushort* __restrict__ wqb,
                                                const ushort* __restrict__ xnT,
                                                ushort* __restrict__ qt,
                                                ushort* __restrict__ kt,
                                                ushort* __restrict__ vv) {
    int n0 = blockIdx.x * 64;
    int o0 = blockIdx.y * 128;
    int b  = blockIdx.z;
    int t = threadIdx.x;
    int w = t >> 6, lane = t & 63, l16 = lane & 15, lg = lane >> 4;
    const ushort* xb = xnT + ((size_t)b * HW_ + n0) * C_;
    const ushort* wrow0 = wqb + (size_t)(o0 + 32 * w + l16) * C_;
    const ushort* wrow1 = wrow0 + 16 * C_;

    f32x4 acc[2][4];
#pragma unroll
    for (int os = 0; os < 2; ++os)
#pragma unroll
        for (int u = 0; u < 4; ++u)
#pragma unroll
            for (int r = 0; r < 4; ++r) acc[os][u][r] = 0.f;

#pragma unroll 2
    for (int ks = 0; ks < 8; ++ks) {
        short8 a0 = *(const short8*)(wrow0 + 32 * ks + 8 * lg);
        short8 a1 = *(const short8*)(wrow1 + 32 * ks + 8 * lg);
#pragma unroll
        for (int u = 0; u < 4; ++u) {
            short8 bf = *(const short8*)(xb + (size_t)(16 * u + l16) * C_ + 32 * ks + 8 * lg);
            acc[0][u] = __builtin_amdgcn_mfma_f32_16x16x32_bf16(a0, bf, acc[0][u], 0, 0, 0);
            acc[1][u] = __builtin_amdgcn_mfma_f32_16x16x32_bf16(a1, bf, acc[1][u], 0, 0, 0);
        }
    }

    int z = o0 >> 8;   // 0:Q 1:K 2:V
#pragma unroll
    for (int os = 0; os < 2; ++os) {
        int o_base = o0 + 32 * w + 16 * os;
        if (z < 2) {
            int h = (o_base >> 6) & 3;
            int od0 = (o_base & 63) + 4 * lg;
            ushort* dstb = (z ? kt : qt) + ((size_t)((b << 2) | h) * HW_) * DH_;
#pragma unroll
            for (int u = 0; u < 4; ++u) {
                int n = n0 + 16 * u + l16;
                uint2 pk;
                pk.x = cvt_pk_bf16(acc[os][u][0], acc[os][u][1]);
                pk.y = cvt_pk_bf16(acc[os][u][2], acc[os][u][3]);
                *(uint2*)(dstb + (size_t)n * DH_ + od0) = pk;
            }
        } else {
            int row0 = o_base - 512 + 4 * lg;
#pragma unroll
            for (int u = 0; u < 4; ++u) {
                int n = n0 + 16 * u + l16;
#pragma unroll
                for (int r = 0; r < 4; ++r)
                    vv[((size_t)(b * C_ + row0 + r)) * HW_ + n] = f2bf(acc[os][u][r]);
            }
        }
    }
}

// ---------------- MFMA flash attention v5: 64-row tiles, 4 blocks/CU -------
// grid 1024 (XCD-swizzled): 16 bh x 64 i-tiles of 64 rows. 4 waves x 16 rows.
// K staged permuted (register-P), V natural; both LDS dbuf. Vote-guarded
// defer-max (no cross-lane max in common path). Literal-cur unroll-2 so the
// dbuf flip folds into ds_read immediate offsets.
__global__ __launch_bounds__(256) void flash_attn_mfma(const ushort* __restrict__ qt,
                                                       const ushort* __restrict__ kt,
                                                       const ushort* __restrict__ vv,
                                                       ushort* __restrict__ attT) {
    __shared__ __align__(16) ushort Kb[2][64 * 64];   // [row perm][dh], chunks swz
    __shared__ __align__(16) ushort Vb[2][64 * 64];   // [d][j],  chunks swz

    int bid = blockIdx.x;
    int wg = (bid & 7) * 128 + (bid >> 3);   // bijective: 1024 = 8 * 128
    int bh = wg >> 6;                         // 64 wg per bh
    int i0 = (wg & 63) * 64;
    int b = bh >> 2, h = bh & 3;
    int t = threadIdx.x;
    int w = t >> 6, lane = t & 63, l16 = lane & 15, lg = lane >> 4;
    const ushort* qtb = qt + (size_t)bh * HW_ * DH_;
    const ushort* ktb = kt + (size_t)bh * HW_ * DH_;
    const ushort* vb  = vv + ((size_t)(b * C_) + h * DH_) * HW_;

    short8 qf[2];
#pragma unroll
    for (int ks = 0; ks < 2; ++ks)
        qf[ks] = *(const short8*)(qtb + (size_t)(i0 + 16 * w + l16) * DH_ + 32 * ks + 8 * lg);

    f32x4 O[4];
#pragma unroll
    for (int dt = 0; dt < 4; ++dt)
#pragma unroll
        for (int r = 0; r < 4; ++r) O[dt][r] = 0.f;
    float m = -1e30f, l = 0.f;

    // per-lane constant staging offsets (K uses row-permutation g(L))
    int r8 = lane >> 3, ch8 = lane & 7;
    size_t koff[2], voff[2];
#pragma unroll
    for (int half = 0; half < 2; ++half) {
        int L = 16 * w + half * 8 + r8;                          // K LDS row
        int gk = (L & 0x23) | ((L & 0x0C) << 1) | ((L & 0x10) >> 2); // src row
        koff[half] = (size_t)gk * DH_ + ((ch8 ^ (L & 7)) << 3);
        voff[half] = (size_t)L * HW_ + ((ch8 ^ (L & 7)) << 3);   // V natural
    }

    auto stage = [&](int bi, int j0) {
#pragma unroll
        for (int half = 0; half < 2; ++half) {
            int rowb = 16 * w + half * 8;
            __builtin_amdgcn_global_load_lds((gas1_t)(ktb + (size_t)j0 * DH_ + koff[half]),
                (las3_t)&Kb[bi][rowb * 64], 16, 0, 0);
            __builtin_amdgcn_global_load_lds((gas1_t)(vb + (size_t)j0 + voff[half]),
                (las3_t)&Vb[bi][rowb * 64], 16, 0, 0);
        }
    };

    // softmax + in-register P-frag build; vote-guarded defer-max
    auto softmax_pf = [&](f32x4* S, short8* pf) {
        float mxa = fmaxf(fmaxf(S[0][0], S[0][1]), fmaxf(S[0][2], S[0][3]));
        float mxb = fmaxf(fmaxf(S[1][0], S[1][1]), fmaxf(S[1][2], S[1][3]));
        float mxc = fmaxf(fmaxf(S[2][0], S[2][1]), fmaxf(S[2][2], S[2][3]));
        float mxd = fmaxf(fmaxf(S[3][0], S[3][1]), fmaxf(S[3][2], S[3][3]));
        float lmax = fmaxf(fmaxf(mxa, mxb), fmaxf(mxc, mxd));
        if (!__all(lmax <= m + 8.f)) {           // rare after tile 0
            float mx = fmaxf(lmax, __shfl_xor(lmax, 16, 64));
            mx = fmaxf(mx, __shfl_xor(mx, 32, 64));
            float mn = fmaxf(m, mx);
            float alpha = __builtin_amdgcn_exp2f(m - mn);
            l *= alpha;
            m = mn;
#pragma unroll
            for (int dt = 0; dt < 4; ++dt)
#pragma unroll
                for (int r = 0; r < 4; ++r) O[dt][r] *= alpha;
        }
        float rs = 0.f;
#pragma unroll
        for (int jt = 0; jt < 4; ++jt) {
#pragma unroll
            for (int r = 0; r < 4; ++r)
                S[jt][r] = __builtin_amdgcn_exp2f(S[jt][r] - m);
            rs += (S[jt][0] + S[jt][1]) + (S[jt][2] + S[jt][3]);
        }
        l += rs;                                  // per-lane partial
#pragma unroll
        for (int ks = 0; ks < 2; ++ks) {
            u32x4 p;
            p[0] = cvt_pk_bf16(S[2 * ks][0],     S[2 * ks][1]);
            p[1] = cvt_pk_bf16(S[2 * ks][2],     S[2 * ks][3]);
            p[2] = cvt_pk_bf16(S[2 * ks + 1][0], S[2 * ks + 1][1]);
            p[3] = cvt_pk_bf16(S[2 * ks + 1][2], S[2 * ks + 1][3]);
            pf[ks] = __builtin_bit_cast(short8, p);
        }
    };

    // one j-tile with compile-time buffer index (folds into ds_read offsets)
    auto tile_body = [&](int curc, int tt) {
        if (tt + 1 < NT_) stage(curc ^ 1, (tt + 1) * 64);

        f32x4 S[4];
        __builtin_amdgcn_s_setprio(1);
#pragma unroll
        for (int jt = 0; jt < 4; ++jt) {
#pragma unroll
            for (int r = 0; r < 4; ++r) S[jt][r] = 0.f;
#pragma unroll
            for (int ks = 0; ks < 2; ++ks) {
                short8 kf = *(const short8*)&Kb[curc][(16 * jt + l16) * 64 +
                                                      (((4 * ks + lg) ^ (l16 & 7)) << 3)];
                S[jt] = __builtin_amdgcn_mfma_f32_16x16x32_bf16(kf, qf[ks], S[jt], 0, 0, 0);
            }
        }
        __builtin_amdgcn_s_setprio(0);

        short8 pf[2];
        softmax_pf(S, pf);

        __builtin_amdgcn_s_setprio(1);
#pragma unroll
        for (int dt = 0; dt < 4; ++dt) {
#pragma unroll
            for (int ks = 0; ks < 2; ++ks) {
                short8 vf = *(const short8*)&Vb[curc][(16 * dt + l16) * 64 +
                                                      (((4 * ks + lg) ^ (l16 & 7)) << 3)];
                O[dt] = __builtin_amdgcn_mfma_f32_16x16x32_bf16(vf, pf[ks], O[dt], 0, 0, 0);
            }
        }
        __builtin_amdgcn_s_setprio(0);

        asm volatile("s_waitcnt vmcnt(0)" ::: "memory");
        __builtin_amdgcn_s_barrier();
    };

    stage(0, 0);
    asm volatile("s_waitcnt vmcnt(0)" ::: "memory");
    __builtin_amdgcn_s_barrier();

    for (int t8 = 0; t8 < NT_; t8 += 2) {
        tile_body(0, t8);
        tile_body(1, t8 + 1);
    }

    // ---- epilogue: reduce per-lane l across lg groups, write attT bf16 ----
    l += __shfl_xor(l, 16, 64);
    l += __shfl_xor(l, 32, 64);
    float inv = 1.f / l;
    ushort* ab = attT + ((size_t)b * HW_ + i0 + 16 * w + l16) * C_ + h * DH_;
#pragma unroll
    for (int dt = 0; dt < 4; ++dt) {
        uint2 p0;
        p0.x = cvt_pk_bf16(O[dt][0] * inv, O[dt][1] * inv);
        p0.y = cvt_pk_bf16(O[dt][2] * inv, O[dt][3] * inv);
        *(uint2*)(ab + 16 * dt + 4 * lg) = p0;
    }
}

// ---------------- proj GEMM (bf16 MFMA) + bias + residual ------------------
__global__ __launch_bounds__(256) void proj_gemm(const ushort* __restrict__ wpb,
                                                 const ushort* __restrict__ attT,
                                                 const float* __restrict__ bias,
                                                 const float* __restrict__ x,
                                                 float* __restrict__ out) {
    int n0 = blockIdx.x * 64;
    int o0 = blockIdx.y * 128;
    int b  = blockIdx.z;
    int t = threadIdx.x;
    int w = t >> 6, lane = t & 63, l16 = lane & 15, lg = lane >> 4;
    const ushort* xb = attT + ((size_t)b * HW_ + n0) * C_;
    const ushort* wrow0 = wpb + (size_t)(o0 + 32 * w + l16) * C_;
    const ushort* wrow1 = wrow0 + 16 * C_;

    f32x4 acc[2][4];
#pragma unroll
    for (int os = 0; os < 2; ++os)
#pragma unroll
        for (int u = 0; u < 4; ++u)
#pragma unroll
            for (int r = 0; r < 4; ++r) acc[os][u][r] = 0.f;

#pragma unroll 2
    for (int ks = 0; ks < 8; ++ks) {
        short8 a0 = *(const short8*)(wrow0 + 32 * ks + 8 * lg);
        short8 a1 = *(const short8*)(wrow1 + 32 * ks + 8 * lg);
#pragma unroll
        for (int u = 0; u < 4; ++u) {
            short8 bf = *(const short8*)(xb + (size_t)(16 * u + l16) * C_ + 32 * ks + 8 * lg);
            acc[0][u] = __builtin_amdgcn_mfma_f32_16x16x32_bf16(a0, bf, acc[0][u], 0, 0, 0);
            acc[1][u] = __builtin_amdgcn_mfma_f32_16x16x32_bf16(a1, bf, acc[1][u], 0, 0, 0);
        }
    }

#pragma unroll
    for (int os = 0; os < 2; ++os) {
        int o_base = o0 + 32 * w + 16 * os;
#pragma unroll
        for (int u = 0; u < 4; ++u) {
            int n = n0 + 16 * u + l16;
#pragma unroll
            for (int r = 0; r < 4; ++r) {
                int mrow = o_base + 4 * lg + r;
                size_t idx = ((size_t)(b * C_ + mrow)) * HW_ + n;
                out[idx] = acc[os][u][r] + bias[mrow] + x[idx];
            }
        }
    }
}

extern "C" void kernel_launch(void* const* d_in, const int* in_sizes, int n_in,
                              void* d_out, int out_size, void* d_ws, size_t ws_size,
                              hipStream_t stream) {
    const float* x        = (const float*)d_in[0];
    const float* gn_gamma = (const float*)d_in[1];
    const float* gn_beta  = (const float*)d_in[2];
    const float* w_qkv    = (const float*)d_in[3];
    const float* w_proj   = (const float*)d_in[4];
    const float* b_proj   = (const float*)d_in[5];
    float* out = (float*)d_out;

    ushort* wsp  = (ushort*)d_ws;
    ushort* xnT  = wsp;                       // 4*4096*256
    ushort* qt   = xnT  + 4194304;            // 16*4096*64
    ushort* kt   = qt   + 4194304;
    ushort* vv   = kt   + 4194304;            // 4*256*4096
    ushort* attT = vv   + 4194304;            // 4*4096*256
    ushort* wqb  = attT + 4194304;            // 768*256
    ushort* wpb  = wqb  + 196608;             // 256*256
    float*  part = (float*)(wpb + 65536);     // 512 floats

    gn_partial<<<dim3(G_ * B_ * NCHUNK), 256, 0, stream>>>(x, part);
    wcvt<<<dim3(1024), 256, 0, stream>>>(w_qkv, w_proj, wqb, wpb);
    gn_xt<<<dim3(HW_ / 64, C_ / 64, B_), 256, 0, stream>>>(x, gn_gamma, gn_beta, part, xnT);
    qkv_gemm<<<dim3(HW_ / 64, 6, B_), 256, 0, stream>>>(wqb, xnT, qt, kt, vv);
    flash_attn_mfma<<<dim3(1024), 256, 0, stream>>>(qt, kt, vv, attT);
    proj_gemm<<<dim3(HW_ / 64, 2, B_), 256, 0, stream>>>(wpb, attT, b_proj, x, out);
}

// Round 9
// 164.301 us; speedup vs baseline: 2.4722x; 1.0258x over previous
//
#include <hip/hip_runtime.h>
#include <math.h>
#include <stdint.h>

#define B_ 4
#define C_ 256
#define HW_ 4096
#define G_ 8
#define H_ 4
#define DH_ 64
#define GRP_ELEMS (32 * HW_)             // 131072
#define NCHUNK 16
#define CHUNK_ELEMS (GRP_ELEMS / NCHUNK) // 8192
#define EPS 1e-5f
#define NT_ (HW_ / 64)                   // 64 j-tiles
#define QSCALE 0.04508422f               // (1/32) * log2(e)

typedef __attribute__((ext_vector_type(8))) short short8;
typedef __attribute__((ext_vector_type(4))) float f32x4;
typedef __attribute__((ext_vector_type(4))) unsigned int u32x4;
typedef const __attribute__((address_space(1))) uint32_t* gas1_t;
typedef __attribute__((address_space(3))) uint32_t* las3_t;

__device__ __forceinline__ ushort f2bf(float x) {
    unsigned u = __builtin_bit_cast(unsigned, x);
    u += 0x7FFFu + ((u >> 16) & 1u);
    return (ushort)(u >> 16);
}
__device__ __forceinline__ uint32_t cvt_pk_bf16(float lo, float hi) {
    uint32_t r;
    asm("v_cvt_pk_bf16_f32 %0, %1, %2" : "=v"(r) : "v"(lo), "v"(hi));
    return r;
}

// ---------------- GroupNorm stage 1: deterministic partial sums -----------
__global__ __launch_bounds__(256) void gn_partial(const float* __restrict__ x,
                                                  float* __restrict__ part) {
    int bg = blockIdx.x >> 4;
    int chunk = blockIdx.x & 15;
    const float4* p = (const float4*)(x + (size_t)bg * GRP_ELEMS + (size_t)chunk * CHUNK_ELEMS);
    int t = threadIdx.x;
    float s = 0.f, ss = 0.f;
#pragma unroll
    for (int i = 0; i < 8; ++i) {
        float4 v = p[t + i * 256];
        s  += v.x + v.y + v.z + v.w;
        ss += v.x * v.x + v.y * v.y + v.z * v.z + v.w * v.w;
    }
#pragma unroll
    for (int off = 32; off; off >>= 1) {
        s  += __shfl_xor(s, off, 64);
        ss += __shfl_xor(ss, off, 64);
    }
    __shared__ float ls[8];
    int wave = t >> 6, lane = t & 63;
    if (lane == 0) { ls[wave * 2] = s; ls[wave * 2 + 1] = ss; }
    __syncthreads();
    if (t == 0) {
        float S = 0.f, SS = 0.f;
#pragma unroll
        for (int w = 0; w < 4; ++w) { S += ls[w * 2]; SS += ls[w * 2 + 1]; }
        part[(bg * 16 + chunk) * 2]     = S;
        part[(bg * 16 + chunk) * 2 + 1] = SS;
    }
}

// ---------------- weight convert f32 -> bf16 (Q rows pre-scaled) ----------
__global__ __launch_bounds__(256) void wcvt(const float* __restrict__ wq,
                                            const float* __restrict__ wp,
                                            ushort* __restrict__ wqb,
                                            ushort* __restrict__ wpb) {
    int i = blockIdx.x * 256 + threadIdx.x;
    if (i < 768 * 256) {
        float s = (i < 256 * 256) ? QSCALE : 1.0f;
        wqb[i] = f2bf(wq[i] * s);
    } else {
        int j = i - 768 * 256;
        wpb[j] = f2bf(wp[j]);
    }
}

// ---------------- GroupNorm + transpose:  x[b][c][n] f32 -> xnT[b][n][c] bf16
__global__ __launch_bounds__(256) void gn_xt(const float* __restrict__ x,
                                             const float* __restrict__ gamma,
                                             const float* __restrict__ beta,
                                             const float* __restrict__ part,
                                             ushort* __restrict__ xnT) {
    __shared__ float2 affs[64];
    __shared__ __align__(16) ushort Ts[64 * 72];
    int n0 = blockIdx.x * 64;
    int c0 = blockIdx.y * 64;
    int b  = blockIdx.z;
    int t = threadIdx.x;
    if (t < 64) {
        int c = c0 + t;
        int bg = b * G_ + (c >> 5);
        float S = 0.f, SS = 0.f;
#pragma unroll
        for (int i = 0; i < 16; ++i) {
            S  += part[(bg * 16 + i) * 2];
            SS += part[(bg * 16 + i) * 2 + 1];
        }
        float mean = S * (1.f / GRP_ELEMS);
        float var  = SS * (1.f / GRP_ELEMS) - mean * mean;
        float inv  = rsqrtf(var + EPS);
        float a = inv * gamma[c];
        affs[t] = make_float2(a, beta[c] - mean * a);
    }
    __syncthreads();
    int n4 = t & 15, cr = t >> 4;
#pragma unroll
    for (int ct = 0; ct < 4; ++ct) {
        int c = cr + 16 * ct;
        float2 p = affs[c];
        float4 v = *(const float4*)(x + ((size_t)(b * C_ + c0 + c)) * HW_ + n0 + n4 * 4);
        ushort e[4];
        e[0] = f2bf(v.x * p.x + p.y); e[1] = f2bf(v.y * p.x + p.y);
        e[2] = f2bf(v.z * p.x + p.y); e[3] = f2bf(v.w * p.x + p.y);
#pragma unroll
        for (int k = 0; k < 4; ++k) {
            int n = n4 * 4 + k;
            Ts[n * 72 + (((c >> 3) ^ ((n >> 2) & 7)) << 3) + (c & 7)] = e[k];
        }
    }
    __syncthreads();
#pragma unroll
    for (int nt = 0; nt < 2; ++nt) {
        int n = (t >> 3) + 32 * nt, c8 = t & 7;
        uint4 val = *(const uint4*)&Ts[n * 72 + ((c8 ^ ((n >> 2) & 7)) << 3)];
        *(uint4*)(xnT + ((size_t)b * HW_ + n0 + n) * C_ + c0 + c8 * 8) = val;
    }
}

// ---------------- QKV GEMM (bf16 MFMA, no LDS) -----------------------------
__global__ __launch_bounds__(256) void qkv_gemm(const ushort* __restrict__ wqb,
                                                const ushort* __restrict__ xnT,
                                                ushort* __restrict__ qt,
                                                ushort* __restrict__ kt,
                                                ushort* __restrict__ vv) {
    int n0 = blockIdx.x * 64;
    int o0 = blockIdx.y * 128;
    int b  = blockIdx.z;
    int t = threadIdx.x;
    int w = t >> 6, lane = t & 63, l16 = lane & 15, lg = lane >> 4;
    const ushort* xb = xnT + ((size_t)b * HW_ + n0) * C_;
    const ushort* wrow0 = wqb + (size_t)(o0 + 32 * w + l16) * C_;
    const ushort* wrow1 = wrow0 + 16 * C_;

    f32x4 acc[2][4];
#pragma unroll
    for (int os = 0; os < 2; ++os)
#pragma unroll
        for (int u = 0; u < 4; ++u)
#pragma unroll
            for (int r = 0; r < 4; ++r) acc[os][u][r] = 0.f;

#pragma unroll 2
    for (int ks = 0; ks < 8; ++ks) {
        short8 a0 = *(const short8*)(wrow0 + 32 * ks + 8 * lg);
        short8 a1 = *(const short8*)(wrow1 + 32 * ks + 8 * lg);
#pragma unroll
        for (int u = 0; u < 4; ++u) {
            short8 bf = *(const short8*)(xb + (size_t)(16 * u + l16) * C_ + 32 * ks + 8 * lg);
            acc[0][u] = __builtin_amdgcn_mfma_f32_16x16x32_bf16(a0, bf, acc[0][u], 0, 0, 0);
            acc[1][u] = __builtin_amdgcn_mfma_f32_16x16x32_bf16(a1, bf, acc[1][u], 0, 0, 0);
        }
    }

    int z = o0 >> 8;   // 0:Q 1:K 2:V
#pragma unroll
    for (int os = 0; os < 2; ++os) {
        int o_base = o0 + 32 * w + 16 * os;
        if (z < 2) {
            int h = (o_base >> 6) & 3;
            int od0 = (o_base & 63) + 4 * lg;
            ushort* dstb = (z ? kt : qt) + ((size_t)((b << 2) | h) * HW_) * DH_;
#pragma unroll
            for (int u = 0; u < 4; ++u) {
                int n = n0 + 16 * u + l16;
                uint2 pk;
                pk.x = cvt_pk_bf16(acc[os][u][0], acc[os][u][1]);
                pk.y = cvt_pk_bf16(acc[os][u][2], acc[os][u][3]);
                *(uint2*)(dstb + (size_t)n * DH_ + od0) = pk;
            }
        } else {
            int row0 = o_base - 512 + 4 * lg;
#pragma unroll
            for (int u = 0; u < 4; ++u) {
                int n = n0 + 16 * u + l16;
#pragma unroll
                for (int r = 0; r < 4; ++r)
                    vv[((size_t)(b * C_ + row0 + r)) * HW_ + n] = f2bf(acc[os][u][r]);
            }
        }
    }
}

// ---------------- MFMA flash attention v6: 2-deep S pipeline ---------------
// grid 1024 (XCD-swizzled): 16 bh x 64 i-tiles of 64 rows. 4 waves x 16 rows.
// Per iter t: stage V(t+1) -> QK(t+1) [results unused until next iter] ->
// stage K(t+2) -> softmax(t) [VALU overlaps QK MFMA] -> PV(t) -> vmcnt+bar.
__global__ __launch_bounds__(256) void flash_attn_mfma(const ushort* __restrict__ qt,
                                                       const ushort* __restrict__ kt,
                                                       const ushort* __restrict__ vv,
                                                       ushort* __restrict__ attT) {
    __shared__ __align__(16) ushort Kb[2][64 * 64];   // [row perm][dh], chunks swz
    __shared__ __align__(16) ushort Vb[2][64 * 64];   // [d][j],  chunks swz

    int bid = blockIdx.x;
    int wg = (bid & 7) * 128 + (bid >> 3);   // bijective: 1024 = 8 * 128
    int bh = wg >> 6;
    int i0 = (wg & 63) * 64;
    int b = bh >> 2, h = bh & 3;
    int t = threadIdx.x;
    int w = t >> 6, lane = t & 63, l16 = lane & 15, lg = lane >> 4;
    const ushort* qtb = qt + (size_t)bh * HW_ * DH_;
    const ushort* ktb = kt + (size_t)bh * HW_ * DH_;
    const ushort* vb  = vv + ((size_t)(b * C_) + h * DH_) * HW_;

    short8 qf[2];
#pragma unroll
    for (int ks = 0; ks < 2; ++ks)
        qf[ks] = *(const short8*)(qtb + (size_t)(i0 + 16 * w + l16) * DH_ + 32 * ks + 8 * lg);

    f32x4 O[4];
#pragma unroll
    for (int dt = 0; dt < 4; ++dt)
#pragma unroll
        for (int r = 0; r < 4; ++r) O[dt][r] = 0.f;
    float m = -1e30f, l = 0.f;

    // per-lane constant staging offsets (K uses row-permutation g(L))
    int r8 = lane >> 3, ch8 = lane & 7;
    size_t koff[2], voff[2];
#pragma unroll
    for (int half = 0; half < 2; ++half) {
        int L = 16 * w + half * 8 + r8;                          // K LDS row
        int gk = (L & 0x23) | ((L & 0x0C) << 1) | ((L & 0x10) >> 2); // src row
        koff[half] = (size_t)gk * DH_ + ((ch8 ^ (L & 7)) << 3);
        voff[half] = (size_t)L * HW_ + ((ch8 ^ (L & 7)) << 3);   // V natural
    }

    auto stageK = [&](int bi, int j0) {
#pragma unroll
        for (int half = 0; half < 2; ++half) {
            int rowb = 16 * w + half * 8;
            __builtin_amdgcn_global_load_lds((gas1_t)(ktb + (size_t)j0 * DH_ + koff[half]),
                (las3_t)&Kb[bi][rowb * 64], 16, 0, 0);
        }
    };
    auto stageV = [&](int bi, int j0) {
#pragma unroll
        for (int half = 0; half < 2; ++half) {
            int rowb = 16 * w + half * 8;
            __builtin_amdgcn_global_load_lds((gas1_t)(vb + (size_t)j0 + voff[half]),
                (las3_t)&Vb[bi][rowb * 64], 16, 0, 0);
        }
    };

    auto qk = [&](int bi, f32x4* S) {
        __builtin_amdgcn_s_setprio(1);
#pragma unroll
        for (int jt = 0; jt < 4; ++jt) {
#pragma unroll
            for (int r = 0; r < 4; ++r) S[jt][r] = 0.f;
#pragma unroll
            for (int ks = 0; ks < 2; ++ks) {
                short8 kf = *(const short8*)&Kb[bi][(16 * jt + l16) * 64 +
                                                    (((4 * ks + lg) ^ (l16 & 7)) << 3)];
                S[jt] = __builtin_amdgcn_mfma_f32_16x16x32_bf16(kf, qf[ks], S[jt], 0, 0, 0);
            }
        }
        __builtin_amdgcn_s_setprio(0);
    };

    auto pv = [&](int bi, short8* pf) {
        __builtin_amdgcn_s_setprio(1);
#pragma unroll
        for (int dt = 0; dt < 4; ++dt) {
#pragma unroll
            for (int ks = 0; ks < 2; ++ks) {
                short8 vf = *(const short8*)&Vb[bi][(16 * dt + l16) * 64 +
                                                    (((4 * ks + lg) ^ (l16 & 7)) << 3)];
                O[dt] = __builtin_amdgcn_mfma_f32_16x16x32_bf16(vf, pf[ks], O[dt], 0, 0, 0);
            }
        }
        __builtin_amdgcn_s_setprio(0);
    };

    // softmax + in-register P-frag build; vote-guarded defer-max; max3 triples
    auto softmax_pf = [&](f32x4* S, short8* pf) {
        float x0 = fmaxf(fmaxf(S[0][0], S[0][1]), S[0][2]);
        float x1 = fmaxf(fmaxf(S[0][3], S[1][0]), S[1][1]);
        float x2 = fmaxf(fmaxf(S[1][2], S[1][3]), S[2][0]);
        float x3 = fmaxf(fmaxf(S[2][1], S[2][2]), S[2][3]);
        float x4 = fmaxf(fmaxf(S[3][0], S[3][1]), S[3][2]);
        float lmax = fmaxf(fmaxf(fmaxf(x0, x1), x2), fmaxf(fmaxf(x3, x4), S[3][3]));
        if (!__all(lmax <= m + 8.f)) {           // rare after tile 0
            float mx = fmaxf(lmax, __shfl_xor(lmax, 16, 64));
            mx = fmaxf(mx, __shfl_xor(mx, 32, 64));
            float mn = fmaxf(m, mx);
            float alpha = __builtin_amdgcn_exp2f(m - mn);
            l *= alpha;
            m = mn;
#pragma unroll
            for (int dt = 0; dt < 4; ++dt)
#pragma unroll
                for (int r = 0; r < 4; ++r) O[dt][r] *= alpha;
        }
        float rs = 0.f;
#pragma unroll
        for (int jt = 0; jt < 4; ++jt) {
#pragma unroll
            for (int r = 0; r < 4; ++r)
                S[jt][r] = __builtin_amdgcn_exp2f(S[jt][r] - m);
            rs += (S[jt][0] + S[jt][1]) + (S[jt][2] + S[jt][3]);
        }
        l += rs;                                  // per-lane partial
#pragma unroll
        for (int ks = 0; ks < 2; ++ks) {
            u32x4 p;
            p[0] = cvt_pk_bf16(S[2 * ks][0],     S[2 * ks][1]);
            p[1] = cvt_pk_bf16(S[2 * ks][2],     S[2 * ks][3]);
            p[2] = cvt_pk_bf16(S[2 * ks + 1][0], S[2 * ks + 1][1]);
            p[3] = cvt_pk_bf16(S[2 * ks + 1][2], S[2 * ks + 1][3]);
            pf[ks] = __builtin_bit_cast(short8, p);
        }
    };

    f32x4 Sa[4], Sb[4];

    // body: softmax+PV tile t, QK tile t+1. B0 = t&1 (literal), B1 = (t+1)&1.
    auto body = [&](int B0, int B1, f32x4* S_CUR, f32x4* S_NXT, int tt) {
        stageV(B1, (tt + 1) * 64);               // V(t+1); Vb[B1] free since bar(t-1)
        qk(B1, S_NXT);                           // QK(t+1); S_NXT unread this iter
        if (tt + 2 < NT_) stageK(B0, (tt + 2) * 64);  // K(t+2); Kb[B0] consumed @ t-1
        short8 pf[2];
        softmax_pf(S_CUR, pf);                   // VALU overlaps QK MFMA drain
        pv(B0, pf);                              // PV(t) from Vb[B0]
        asm volatile("s_waitcnt vmcnt(0)" ::: "memory");
        __builtin_amdgcn_s_barrier();
    };

    // prologue: K/V(0) -> buf0; QK(0); K(1) -> buf1
    stageK(0, 0); stageV(0, 0);
    asm volatile("s_waitcnt vmcnt(0)" ::: "memory");
    __builtin_amdgcn_s_barrier();
    qk(0, Sa);
    stageK(1, 64);
    asm volatile("s_waitcnt vmcnt(0)" ::: "memory");
    __builtin_amdgcn_s_barrier();

    for (int tp = 0; tp < 31; ++tp) {
        body(0, 1, Sa, Sb, 2 * tp);
        body(1, 0, Sb, Sa, 2 * tp + 1);
    }
    body(0, 1, Sa, Sb, 62);
    {   // tail: tile 63
        short8 pf[2];
        softmax_pf(Sb, pf);
        pv(1, pf);
    }

    // ---- epilogue: reduce per-lane l across lg groups, write attT bf16 ----
    l += __shfl_xor(l, 16, 64);
    l += __shfl_xor(l, 32, 64);
    float inv = 1.f / l;
    ushort* ab = attT + ((size_t)b * HW_ + i0 + 16 * w + l16) * C_ + h * DH_;
#pragma unroll
    for (int dt = 0; dt < 4; ++dt) {
        uint2 p0;
        p0.x = cvt_pk_bf16(O[dt][0] * inv, O[dt][1] * inv);
        p0.y = cvt_pk_bf16(O[dt][2] * inv, O[dt][3] * inv);
        *(uint2*)(ab + 16 * dt + 4 * lg) = p0;
    }
}

// ---------------- proj GEMM (bf16 MFMA) + bias + residual ------------------
__global__ __launch_bounds__(256) void proj_gemm(const ushort* __restrict__ wpb,
                                                 const ushort* __restrict__ attT,
                                                 const float* __restrict__ bias,
                                                 const float* __restrict__ x,
                                                 float* __restrict__ out) {
    int n0 = blockIdx.x * 64;
    int o0 = blockIdx.y * 128;
    int b  = blockIdx.z;
    int t = threadIdx.x;
    int w = t >> 6, lane = t & 63, l16 = lane & 15, lg = lane >> 4;
    const ushort* xb = attT + ((size_t)b * HW_ + n0) * C_;
    const ushort* wrow0 = wpb + (size_t)(o0 + 32 * w + l16) * C_;
    const ushort* wrow1 = wrow0 + 16 * C_;

    f32x4 acc[2][4];
#pragma unroll
    for (int os = 0; os < 2; ++os)
#pragma unroll
        for (int u = 0; u < 4; ++u)
#pragma unroll
            for (int r = 0; r < 4; ++r) acc[os][u][r] = 0.f;

#pragma unroll 2
    for (int ks = 0; ks < 8; ++ks) {
        short8 a0 = *(const short8*)(wrow0 + 32 * ks + 8 * lg);
        short8 a1 = *(const short8*)(wrow1 + 32 * ks + 8 * lg);
#pragma unroll
        for (int u = 0; u < 4; ++u) {
            short8 bf = *(const short8*)(xb + (size_t)(16 * u + l16) * C_ + 32 * ks + 8 * lg);
            acc[0][u] = __builtin_amdgcn_mfma_f32_16x16x32_bf16(a0, bf, acc[0][u], 0, 0, 0);
            acc[1][u] = __builtin_amdgcn_mfma_f32_16x16x32_bf16(a1, bf, acc[1][u], 0, 0, 0);
        }
    }

#pragma unroll
    for (int os = 0; os < 2; ++os) {
        int o_base = o0 + 32 * w + 16 * os;
#pragma unroll
        for (int u = 0; u < 4; ++u) {
            int n = n0 + 16 * u + l16;
#pragma unroll
            for (int r = 0; r < 4; ++r) {
                int mrow = o_base + 4 * lg + r;
                size_t idx = ((size_t)(b * C_ + mrow)) * HW_ + n;
                out[idx] = acc[os][u][r] + bias[mrow] + x[idx];
            }
        }
    }
}

extern "C" void kernel_launch(void* const* d_in, const int* in_sizes, int n_in,
                              void* d_out, int out_size, void* d_ws, size_t ws_size,
                              hipStream_t stream) {
    const float* x        = (const float*)d_in[0];
    const float* gn_gamma = (const float*)d_in[1];
    const float* gn_beta  = (const float*)d_in[2];
    const float* w_qkv    = (const float*)d_in[3];
    const float* w_proj   = (const float*)d_in[4];
    const float* b_proj   = (const float*)d_in[5];
    float* out = (float*)d_out;

    ushort* wsp  = (ushort*)d_ws;
    ushort* xnT  = wsp;                       // 4*4096*256
    ushort* qt   = xnT  + 4194304;            // 16*4096*64
    ushort* kt   = qt   + 4194304;
    ushort* vv   = kt   + 4194304;            // 4*256*4096
    ushort* attT = vv   + 4194304;            // 4*4096*256
    ushort* wqb  = attT + 4194304;            // 768*256
    ushort* wpb  = wqb  + 196608;             // 256*256
    float*  part = (float*)(wpb + 65536);     // 512 floats

    gn_partial<<<dim3(G_ * B_ * NCHUNK), 256, 0, stream>>>(x, part);
    wcvt<<<dim3(1024), 256, 0, stream>>>(w_qkv, w_proj, wqb, wpb);
    gn_xt<<<dim3(HW_ / 64, C_ / 64, B_), 256, 0, stream>>>(x, gn_gamma, gn_beta, part, xnT);
    qkv_gemm<<<dim3(HW_ / 64, 6, B_), 256, 0, stream>>>(wqb, xnT, qt, kt, vv);
    flash_attn_mfma<<<dim3(1024), 256, 0, stream>>>(qt, kt, vv, attT);
    proj_gemm<<<dim3(HW_ / 64, 2, B_), 256, 0, stream>>>(wpb, attT, b_proj, x, out);
}